// Round 15
// baseline (235.155 us; speedup 1.0000x reference)
//
#include <hip/hip_runtime.h>
#include <hip/hip_bf16.h>
#include <stdint.h>

// Attention_9234179687676: x[2,4096,768] -> qkv -> 12-head attn (N=4096, D=64) -> proj+bias
// fp32 in/out, bf16 MFMA internally.

typedef short bf16x8 __attribute__((ext_vector_type(8)));
typedef float f32x4 __attribute__((ext_vector_type(4)));
typedef float f32x16 __attribute__((ext_vector_type(16)));
typedef uint32_t u32x4 __attribute__((ext_vector_type(4)));

#define B_SZ 2
#define NSEQ 4096
#define CDIM 768
#define NH 12
#define DHEAD 64
#define PER_S ((size_t)8192 * 768)

static __device__ __forceinline__ void gload_lds16(const void* g, void* l) {
  __builtin_amdgcn_global_load_lds(
      (const __attribute__((address_space(1))) uint32_t*)g,
      (__attribute__((address_space(3))) uint32_t*)l, 16, 0, 0);
}

// packed f32->bf16 (RNE): 1 instruction for 2 values
static __device__ __forceinline__ uint32_t pack2(float lo, float hi) {
  uint32_t r;
  asm("v_cvt_pk_bf16_f32 %0, %1, %2" : "=v"(r) : "v"(lo), "v"(hi));
  return r;
}

static __device__ __forceinline__ float fexp2(float x) {
#if __has_builtin(__builtin_amdgcn_exp2f)
  return __builtin_amdgcn_exp2f(x);   // raw v_exp_f32
#else
  return exp2f(x);
#endif
}

static __device__ __forceinline__ void permswap(uint32_t& a, uint32_t& b) {
#if __has_builtin(__builtin_amdgcn_permlane32_swap)
  auto r = __builtin_amdgcn_permlane32_swap((int)a, (int)b, false, false);
  a = (uint32_t)r[0];
  b = (uint32_t)r[1];
#else
  asm volatile("v_permlane32_swap_b32 %0, %1" : "+v"(a), "+v"(b));
#endif
}

// ---------------- single fused fp32 -> bf16 convert into contiguous ws region
// regions (float4 units): x [0,1572864) ; wqkv [1572864,2015232) with QSCALE on
// its first 147456 (= 768 Q rows x 768 / 4); wproj [2015232,2162688)
__global__ void cvt_all(const float* __restrict__ x, const float* __restrict__ wqkv,
                        const float* __restrict__ wproj, __hip_bfloat16* __restrict__ dst,
                        float qscale) {
  int i = blockIdx.x * 256 + threadIdx.x;
  if (i >= 2162688) return;
  const float* src;
  int off;
  float sc = 1.0f;
  if (i < 1572864) {
    src = x; off = 0;
  } else if (i < 2015232) {
    src = wqkv; off = 1572864;
    if (i < 1572864 + 147456) sc = qscale;
  } else {
    src = wproj; off = 2015232;
  }
  float4 v = ((const float4*)src)[i - off];
  uint2 o;
  o.x = pack2(v.x * sc, v.y * sc);
  o.y = pack2(v.z * sc, v.w * sc);
  ((uint2*)dst)[i] = o;
}

// ---------------- QKV GEMM  C = A[8192,768] * B[2304,768]^T, 128x128 tiles
// BK=64 (12 barrier periods) + T2 XOR-swizzled LDS (16B unit ^ row&7,
// pre-swizzled on the GLOBAL source, linear LDS dest - m173 pattern).
// MFMA operands swapped (mfma(bf,af)): reg-quad spans 4 consecutive gcols.
__global__ __launch_bounds__(256)
void gemm_qkv(const __hip_bfloat16* __restrict__ A, const __hip_bfloat16* __restrict__ Bw,
              __hip_bfloat16* __restrict__ qkv) {
  __shared__ __hip_bfloat16 As[128 * 64];   // row stride 128B, swizzled
  __shared__ __hip_bfloat16 Bs[128 * 64];
  const int t = threadIdx.x;
  const int lane = t & 63, w = t >> 6, g = lane >> 4, cg = lane & 15;
  const int wr = (w >> 1) * 64, wc = (w & 1) * 64;
  const int tm = blockIdx.x / 18, tn = blockIdx.x % 18;
  const char* Ab = (const char*)A + (size_t)tm * 128 * 768 * 2;
  const char* Bb = (const char*)Bw + (size_t)tn * 128 * 768 * 2;

  f32x4 z = {0.f, 0.f, 0.f, 0.f};
  f32x4 acc[4][4];
#pragma unroll
  for (int mi = 0; mi < 4; ++mi)
#pragma unroll
    for (int ni = 0; ni < 4; ++ni) acc[mi][ni] = z;

  // staging map (per gload slot): row = slot>>7, 16B-unit p = (slot&127)>>4;
  // source k-unit = p ^ (row&7)  -> LDS linear, reads use the same XOR.
  int srow[4], skoff[4];
#pragma unroll
  for (int i = 0; i < 4; ++i) {
    int slot = t * 16 + i * 4096;
    srow[i] = slot >> 7;
    skoff[i] = (((slot & 127) >> 4) ^ (srow[i] & 7)) << 4;
  }
  const int rsw = (cg & 7);

  for (int k0 = 0; k0 < 768; k0 += 64) {
    __syncthreads();
#pragma unroll
    for (int i = 0; i < 4; ++i) {
      int slot = t * 16 + i * 4096;
      gload_lds16(Ab + (size_t)srow[i] * 1536 + k0 * 2 + skoff[i], (char*)As + slot);
      gload_lds16(Bb + (size_t)srow[i] * 1536 + k0 * 2 + skoff[i], (char*)Bs + slot);
    }
    asm volatile("s_waitcnt vmcnt(0)" ::: "memory");
    __syncthreads();
#pragma unroll
    for (int h = 0; h < 2; ++h) {
      bf16x8 af[4], bf[4];
#pragma unroll
      for (int mi = 0; mi < 4; ++mi)
        af[mi] = *(const bf16x8*)((const char*)As + (wr + mi * 16 + cg) * 128 +
                                  (((h * 4 + g) ^ rsw) << 4));
#pragma unroll
      for (int ni = 0; ni < 4; ++ni)
        bf[ni] = *(const bf16x8*)((const char*)Bs + (wc + ni * 16 + cg) * 128 +
                                  (((h * 4 + g) ^ rsw) << 4));
#pragma unroll
      for (int mi = 0; mi < 4; ++mi)
#pragma unroll
        for (int ni = 0; ni < 4; ++ni)
          acc[mi][ni] = __builtin_amdgcn_mfma_f32_16x16x32_bf16(bf[ni], af[mi], acc[mi][ni], 0, 0, 0);
    }
  }

  const int b = (tm * 128) >> 12;
  const int nb = (tm * 128) & 4095;
#pragma unroll
  for (int mi = 0; mi < 4; ++mi)
#pragma unroll
    for (int ni = 0; ni < 4; ++ni) {
      int gcolb = tn * 128 + wc + ni * 16 + g * 4;     // quad base (4 consecutive cols)
      int s = gcolb / CDIM, hd = gcolb % CDIM;
      int h = hd >> 6, d = hd & 63;
      int n = nb + wr + mi * 16 + cg;
      if (s == 2) {
#pragma unroll
        for (int r = 0; r < 4; ++r) {
          size_t dst = 2 * PER_S + ((size_t)(b * NH + h) * DHEAD + d + r) * NSEQ + n;
          qkv[dst] = __float2bfloat16(acc[mi][ni][r]);
        }
      } else {
        uint2 o;
        o.x = pack2(acc[mi][ni][0], acc[mi][ni][1]);
        o.y = pack2(acc[mi][ni][2], acc[mi][ni][3]);
        size_t dst = (size_t)s * PER_S + ((size_t)(b * NH + h) * NSEQ + n) * DHEAD + d;
        *(uint2*)(qkv + dst) = o;
      }
    }
}

// ---------------- proj GEMM  C = A[8192,768] * B[768,768]^T + bias, 64x128 tiles
// BK=64 + same T2 swizzle. Swapped operands -> float4 C-stores. 768 blocks = 3/CU.
__global__ __launch_bounds__(256)
void gemm_proj(const __hip_bfloat16* __restrict__ A, const __hip_bfloat16* __restrict__ Bw,
               float* __restrict__ Cf, const float* __restrict__ bias) {
  __shared__ __hip_bfloat16 As[64 * 64];    // row stride 128B, swizzled
  __shared__ __hip_bfloat16 Bs[128 * 64];
  const int t = threadIdx.x;
  const int lane = t & 63, w = t >> 6, g = lane >> 4, cg = lane & 15;
  const int tm = blockIdx.x / 6, tn = blockIdx.x % 6;
  const char* Ab = (const char*)A + (size_t)tm * 64 * 768 * 2;
  const char* Bb = (const char*)Bw + (size_t)tn * 128 * 768 * 2;

  f32x4 z = {0.f, 0.f, 0.f, 0.f};
  f32x4 acc[4][2];
#pragma unroll
  for (int mi = 0; mi < 4; ++mi)
#pragma unroll
    for (int ni = 0; ni < 2; ++ni) acc[mi][ni] = z;

  const int rsw = (cg & 7);

  for (int k0 = 0; k0 < 768; k0 += 64) {
    __syncthreads();
#pragma unroll
    for (int i = 0; i < 2; ++i) {   // As: 8KB = 2 slots/thread
      int slot = t * 16 + i * 4096;
      int row = slot >> 7;
      int koff = (((slot & 127) >> 4) ^ (row & 7)) << 4;
      gload_lds16(Ab + (size_t)row * 1536 + k0 * 2 + koff, (char*)As + slot);
    }
#pragma unroll
    for (int i = 0; i < 4; ++i) {   // Bs: 16KB = 4 slots/thread
      int slot = t * 16 + i * 4096;
      int row = slot >> 7;
      int koff = (((slot & 127) >> 4) ^ (row & 7)) << 4;
      gload_lds16(Bb + (size_t)row * 1536 + k0 * 2 + koff, (char*)Bs + slot);
    }
    asm volatile("s_waitcnt vmcnt(0)" ::: "memory");
    __syncthreads();
#pragma unroll
    for (int h = 0; h < 2; ++h) {
      bf16x8 af[4], bf[2];
#pragma unroll
      for (int mi = 0; mi < 4; ++mi)
        af[mi] = *(const bf16x8*)((const char*)As + (mi * 16 + cg) * 128 +
                                  (((h * 4 + g) ^ rsw) << 4));
#pragma unroll
      for (int ni = 0; ni < 2; ++ni)
        bf[ni] = *(const bf16x8*)((const char*)Bs + (w * 32 + ni * 16 + cg) * 128 +
                                  (((h * 4 + g) ^ rsw) << 4));
#pragma unroll
      for (int mi = 0; mi < 4; ++mi)
#pragma unroll
        for (int ni = 0; ni < 2; ++ni)
          acc[mi][ni] = __builtin_amdgcn_mfma_f32_16x16x32_bf16(bf[ni], af[mi], acc[mi][ni], 0, 0, 0);
    }
  }

#pragma unroll
  for (int mi = 0; mi < 4; ++mi)
#pragma unroll
    for (int ni = 0; ni < 2; ++ni) {
      int grow = tm * 64 + mi * 16 + cg;
      int gcol = tn * 128 + w * 32 + ni * 16 + g * 4;
      float4 bv = *(const float4*)(bias + gcol);
      float4 ov;
      ov.x = acc[mi][ni][0] + bv.x;
      ov.y = acc[mi][ni][1] + bv.y;
      ov.z = acc[mi][ni][2] + bv.z;
      ov.w = acc[mi][ni][3] + bv.w;
      *(float4*)(Cf + (size_t)grow * CDIM + gcol) = ov;
    }
}

// ---------------- flash attention, swapped-operand 32x32x16, UNNORMALIZED exp2
// kv-SPLIT variant: block = 4 waves, 64 q rows. Waves {0,1} own q-subtiles
// {0,1} for kv-half 0; waves {2,3} same q for kv-half 1. Per-wave per-tile
// work halves (one 4-MFMA QK^T chain, one pa pair, 4 PV MFMA) while staging
// and barrier structure stay byte-identical. Grid 1536 -> 5 blocks/CU
// resident (LDS 32KB) vs 3 before: TLP hides the dependency-chain stalls.
// kv-half partials combined once at the end via LDS scratch (f32 adds only).
struct QFrag { bf16x8 v[4]; };

static __device__ __forceinline__ void attn_tile_half(const char* __restrict__ Kb,
                                                      const char* __restrict__ Vb,
                                                      const QFrag& qf, int l31, int hi,
                                                      int kvh, const f32x16& Z,
                                                      f32x16& o0, f32x16& o1, float& lsum) {
  const int swz = (l31 & 7) << 4;
  const int krow = kvh * 32 + l31;
  __builtin_amdgcn_s_setprio(1);
  bf16x8 k0 = *(const bf16x8*)(Kb + krow * 128 + ((hi * 16) ^ swz));
  f32x16 t0 = __builtin_amdgcn_mfma_f32_32x32x16_bf16(k0, qf.v[0], Z, 0, 0, 0);
#pragma unroll
  for (int j = 1; j < 4; ++j) {
    bf16x8 kf = *(const bf16x8*)(Kb + krow * 128 + ((j * 32 + hi * 16) ^ swz));
    t0 = __builtin_amdgcn_mfma_f32_32x32x16_bf16(kf, qf.v[j], t0, 0, 0, 0);
  }
  __builtin_amdgcn_s_setprio(0);

#pragma unroll
  for (int r = 0; r < 16; ++r) t0[r] = fexp2(t0[r]);

  // pairwise tree sum of own 16 P values (f32); cross-lane combines in epilogue
  float s0 = ((t0[0] + t0[1]) + (t0[2] + t0[3])) + ((t0[4] + t0[5]) + (t0[6] + t0[7]));
  float s1 = ((t0[8] + t0[9]) + (t0[10] + t0[11])) + ((t0[12] + t0[13]) + (t0[14] + t0[15]));
  lsum += s0 + s1;

  // P -> bf16 A-frags in-register (cvt_pk pairs, permlane32_swap halves)
  uint32_t w0[8];
#pragma unroll
  for (int i = 0; i < 8; ++i) w0[i] = pack2(t0[2 * i], t0[2 * i + 1]);
  permswap(w0[0], w0[2]); permswap(w0[1], w0[3]);
  permswap(w0[4], w0[6]); permswap(w0[5], w0[7]);
  union { u32x4 u; bf16x8 b; } pa[2];
  pa[0].u = (u32x4){w0[0], w0[1], w0[2], w0[3]};
  pa[1].u = (u32x4){w0[4], w0[5], w0[6], w0[7]};

  // O += P V over this wave's 32 kv (A = P-frag, B = V^T-frag from LDS)
  __builtin_amdgcn_s_setprio(1);
#pragma unroll
  for (int j = 0; j < 2; ++j) {
    bf16x8 vf0 = *(const bf16x8*)(Vb + l31 * 128 + ((kvh * 64 + j * 32 + hi * 16) ^ swz));
    bf16x8 vf1 = *(const bf16x8*)(Vb + (32 + l31) * 128 + ((kvh * 64 + j * 32 + hi * 16) ^ swz));
    o0 = __builtin_amdgcn_mfma_f32_32x32x16_bf16(pa[j].b, vf0, o0, 0, 0, 0);
    o1 = __builtin_amdgcn_mfma_f32_32x32x16_bf16(pa[j].b, vf1, o1, 0, 0, 0);
  }
  __builtin_amdgcn_s_setprio(0);
}

__global__ __launch_bounds__(256)
void attn_kernel(const __hip_bfloat16* __restrict__ Qg,   // [bh][n][d]
                 const __hip_bfloat16* __restrict__ Kg,   // [bh][n][d]
                 const __hip_bfloat16* __restrict__ Vtg,  // [bh][d][n]
                 __hip_bfloat16* __restrict__ Og) {
  __shared__ char Ks[2][8192];
  __shared__ char Vs[2][8192];

  const int t = threadIdx.x;
  const int lane = t & 63, w = t >> 6;
  const int l31 = lane & 31, hi = lane >> 5;
  const int wq = w & 1;     // q sub-tile within block
  const int kvh = w >> 1;   // kv half this wave owns

  // bijective XCD swizzle: 1536 blocks, 192/XCD -> each XCD owns 3 whole heads
  const int wg = (blockIdx.x & 7) * 192 + (blockIdx.x >> 3);
  const int bh = wg >> 6, qblk = wg & 63;
  // de-phase-lock co-resident blocks: hashed kv start tile (sum is order-invariant)
  const int start = (int)((wg * 2654435761u) >> 26) & 63;

  const char* Qb = (const char*)Qg + (size_t)bh * (NSEQ * DHEAD * 2);
  const char* Kb = (const char*)Kg + (size_t)bh * (NSEQ * DHEAD * 2);
  const char* Vb = (const char*)Vtg + (size_t)bh * (NSEQ * DHEAD * 2);

  // staging map: LDS slot p -> row=p>>7, col=(p&127); global src col pre-swizzled (m173)
  const int s0 = t * 16, s1 = t * 16 + 4096;
  const int r0 = s0 >> 7, c0 = (s0 & 127) ^ ((r0 & 7) << 4);
  const int r1 = s1 >> 7, c1 = (s1 & 127) ^ ((r1 & 7) << 4);
  const char* ks0 = Kb + r0 * 128 + c0;
  const char* ks1 = Kb + r1 * 128 + c1;
  const char* vs0 = Vb + (size_t)r0 * (NSEQ * 2) + c0;
  const char* vs1 = Vb + (size_t)r1 * (NSEQ * 2) + c1;

#define STAGE(buf, tile)                                            \
  do {                                                              \
    int kv0_ = (tile)*64;                                           \
    gload_lds16(ks0 + (size_t)kv0_ * 128, &Ks[buf][s0]);            \
    gload_lds16(ks1 + (size_t)kv0_ * 128, &Ks[buf][s1]);            \
    gload_lds16(vs0 + kv0_ * 2, &Vs[buf][s0]);                      \
    gload_lds16(vs1 + kv0_ * 2, &Vs[buf][s1]);                      \
  } while (0)

  // Q fragments (B-operand: n=q at lane&31, k=d slice at hi*16), 4 d-slices
  const int q0 = qblk * 64 + wq * 32;
  QFrag qf;
#pragma unroll
  for (int j = 0; j < 4; ++j)
    qf.v[j] = *(const bf16x8*)(Qb + (size_t)(q0 + l31) * 128 + j * 32 + hi * 16);

  f32x16 o0, o1, Z;
#pragma unroll
  for (int r = 0; r < 16; ++r) { o0[r] = 0.f; o1[r] = 0.f; Z[r] = 0.f; }
  float lsum = 0.f;

  STAGE(0, start);
  asm volatile("s_waitcnt vmcnt(0)" ::: "memory");
  __syncthreads();

  for (int i = 0; i < 64; i += 2) {
    STAGE(1, (i + 1 + start) & 63);
    attn_tile_half(Ks[0], Vs[0], qf, l31, hi, kvh, Z, o0, o1, lsum);
    asm volatile("s_waitcnt vmcnt(0)" ::: "memory");
    __syncthreads();
    if (i + 2 < 64) STAGE(0, (i + 2 + start) & 63);
    attn_tile_half(Ks[1], Vs[1], qf, l31, hi, kvh, Z, o0, o1, lsum);
    asm volatile("s_waitcnt vmcnt(0)" ::: "memory");
    __syncthreads();
  }

  // cross-half (lane^32) lsum combine within wave
  {
    uint32_t c = __builtin_bit_cast(uint32_t, lsum), d = c;
    permswap(c, d);
    lsum = __builtin_bit_cast(float, c) + __builtin_bit_cast(float, d);
  }

  // cross-wave (kv-half) combine via LDS scratch (reuse Ks/Vs; all tile reads
  // completed at the final barrier above). Layout [r][wq*64+lane]: conflict-free.
  float* OB = (float*)&Ks[0][0];   // 32 r-slices x 128 lanes x 4B = 16 KB
  float* LB = (float*)&Vs[0][0];   // 128 floats
  if (kvh == 1) {
#pragma unroll
    for (int r = 0; r < 16; ++r) {
      OB[r * 128 + wq * 64 + lane] = o0[r];
      OB[(16 + r) * 128 + wq * 64 + lane] = o1[r];
    }
    LB[wq * 64 + lane] = lsum;
  }
  __syncthreads();
  if (kvh == 0) {
#pragma unroll
    for (int r = 0; r < 16; ++r) {
      o0[r] += OB[r * 128 + wq * 64 + lane];
      o1[r] += OB[(16 + r) * 128 + wq * 64 + lane];
    }
    lsum += LB[wq * 64 + lane];

    float linv = 1.0f / lsum;
    const int b = bh / NH, h = bh % NH;
#pragma unroll
    for (int r = 0; r < 16; ++r) {
      int ql = (r & 3) + 8 * (r >> 2) + 4 * hi;
      float lr = __shfl(linv, ql, 32);
      size_t base = (size_t)(b * NSEQ + q0 + ql) * CDIM + h * DHEAD;
      Og[base + l31] = __float2bfloat16(o0[r] * lr);
      Og[base + 32 + l31] = __float2bfloat16(o1[r] * lr);
    }
  }
#undef STAGE
}

extern "C" void kernel_launch(void* const* d_in, const int* in_sizes, int n_in,
                              void* d_out, int out_size, void* d_ws, size_t ws_size,
                              hipStream_t stream) {
  const float* x = (const float*)d_in[0];
  const float* wqkv = (const float*)d_in[1];
  const float* wproj = (const float*)d_in[2];
  const float* bproj = (const float*)d_in[3];

  char* ws = (char*)d_ws;
  __hip_bfloat16* xb     = (__hip_bfloat16*)(ws);              // 12,582,912 B
  __hip_bfloat16* wqkvb  = (__hip_bfloat16*)(ws + 12582912);   //  3,538,944 B
  __hip_bfloat16* wprojb = (__hip_bfloat16*)(ws + 16121856);   //  1,179,648 B
  __hip_bfloat16* qkvws  = (__hip_bfloat16*)(ws + 17301504);   // 37,748,736 B
  __hip_bfloat16* attnws = (__hip_bfloat16*)(ws + 55050240);   // 12,582,912 B

  const float QSCALE = 0.125f * 1.44269504088896340736f;  // head_dim^-0.5 * log2(e)

  cvt_all<<<8448, 256, 0, stream>>>(x, wqkv, wproj, xb, QSCALE);

  gemm_qkv<<<64 * 18, 256, 0, stream>>>(xb, wqkvb, qkvws);

  attn_kernel<<<1536, 256, 0, stream>>>(qkvws, qkvws + PER_S, qkvws + 2 * PER_S, attnws);

  gemm_proj<<<128 * 6, 256, 0, stream>>>(attnws, wprojb, (float*)d_out, bproj);
}

// Round 16
// 230.900 us; speedup vs baseline: 1.0184x; 1.0184x over previous
//
#include <hip/hip_runtime.h>
#include <hip/hip_bf16.h>
#include <stdint.h>

// Attention_9234179687676: x[2,4096,768] -> qkv -> 12-head attn (N=4096, D=64) -> proj+bias
// fp32 in/out, bf16 MFMA internally.

typedef short bf16x8 __attribute__((ext_vector_type(8)));
typedef float f32x2 __attribute__((ext_vector_type(2)));
typedef float f32x4 __attribute__((ext_vector_type(4)));
typedef float f32x16 __attribute__((ext_vector_type(16)));
typedef uint32_t u32x4 __attribute__((ext_vector_type(4)));

#define B_SZ 2
#define NSEQ 4096
#define CDIM 768
#define NH 12
#define DHEAD 64
#define PER_S ((size_t)8192 * 768)

static __device__ __forceinline__ void gload_lds16(const void* g, void* l) {
  __builtin_amdgcn_global_load_lds(
      (const __attribute__((address_space(1))) uint32_t*)g,
      (__attribute__((address_space(3))) uint32_t*)l, 16, 0, 0);
}

// packed f32->bf16 (RNE): 1 instruction for 2 values
static __device__ __forceinline__ uint32_t pack2(float lo, float hi) {
  uint32_t r;
  asm("v_cvt_pk_bf16_f32 %0, %1, %2" : "=v"(r) : "v"(lo), "v"(hi));
  return r;
}

// packed f32 add (VOP3P): 2 adds / instruction
static __device__ __forceinline__ f32x2 pkadd(f32x2 a, f32x2 b) {
  f32x2 r;
  asm("v_pk_add_f32 %0, %1, %2" : "=v"(r) : "v"(a), "v"(b));
  return r;
}

static __device__ __forceinline__ float fexp2(float x) {
#if __has_builtin(__builtin_amdgcn_exp2f)
  return __builtin_amdgcn_exp2f(x);   // raw v_exp_f32
#else
  return exp2f(x);
#endif
}

static __device__ __forceinline__ void permswap(uint32_t& a, uint32_t& b) {
#if __has_builtin(__builtin_amdgcn_permlane32_swap)
  auto r = __builtin_amdgcn_permlane32_swap((int)a, (int)b, false, false);
  a = (uint32_t)r[0];
  b = (uint32_t)r[1];
#else
  asm volatile("v_permlane32_swap_b32 %0, %1" : "+v"(a), "+v"(b));
#endif
}

// ---------------- single fused fp32 -> bf16 convert into contiguous ws region
// regions (float4 units): x [0,1572864) ; wqkv [1572864,2015232) with QSCALE on
// its first 147456 (= 768 Q rows x 768 / 4); wproj [2015232,2162688)
__global__ void cvt_all(const float* __restrict__ x, const float* __restrict__ wqkv,
                        const float* __restrict__ wproj, __hip_bfloat16* __restrict__ dst,
                        float qscale) {
  int i = blockIdx.x * 256 + threadIdx.x;
  if (i >= 2162688) return;
  const float* src;
  int off;
  float sc = 1.0f;
  if (i < 1572864) {
    src = x; off = 0;
  } else if (i < 2015232) {
    src = wqkv; off = 1572864;
    if (i < 1572864 + 147456) sc = qscale;
  } else {
    src = wproj; off = 2015232;
  }
  float4 v = ((const float4*)src)[i - off];
  uint2 o;
  o.x = pack2(v.x * sc, v.y * sc);
  o.y = pack2(v.z * sc, v.w * sc);
  ((uint2*)dst)[i] = o;
}

// ---------------- QKV GEMM  C = A[8192,768] * B[2304,768]^T, 128x128 tiles
// BK=64 (12 barrier periods) + T2 XOR-swizzled LDS (16B unit ^ row&7,
// pre-swizzled on the GLOBAL source, linear LDS dest - m173 pattern).
// MFMA operands swapped (mfma(bf,af)): reg-quad spans 4 consecutive gcols.
__global__ __launch_bounds__(256)
void gemm_qkv(const __hip_bfloat16* __restrict__ A, const __hip_bfloat16* __restrict__ Bw,
              __hip_bfloat16* __restrict__ qkv) {
  __shared__ __hip_bfloat16 As[128 * 64];   // row stride 128B, swizzled
  __shared__ __hip_bfloat16 Bs[128 * 64];
  const int t = threadIdx.x;
  const int lane = t & 63, w = t >> 6, g = lane >> 4, cg = lane & 15;
  const int wr = (w >> 1) * 64, wc = (w & 1) * 64;
  const int tm = blockIdx.x / 18, tn = blockIdx.x % 18;
  const char* Ab = (const char*)A + (size_t)tm * 128 * 768 * 2;
  const char* Bb = (const char*)Bw + (size_t)tn * 128 * 768 * 2;

  f32x4 z = {0.f, 0.f, 0.f, 0.f};
  f32x4 acc[4][4];
#pragma unroll
  for (int mi = 0; mi < 4; ++mi)
#pragma unroll
    for (int ni = 0; ni < 4; ++ni) acc[mi][ni] = z;

  // staging map (per gload slot): row = slot>>7, 16B-unit p = (slot&127)>>4;
  // source k-unit = p ^ (row&7)  -> LDS linear, reads use the same XOR.
  int srow[4], skoff[4];
#pragma unroll
  for (int i = 0; i < 4; ++i) {
    int slot = t * 16 + i * 4096;
    srow[i] = slot >> 7;
    skoff[i] = (((slot & 127) >> 4) ^ (srow[i] & 7)) << 4;
  }
  const int rsw = (cg & 7);

  for (int k0 = 0; k0 < 768; k0 += 64) {
    __syncthreads();
#pragma unroll
    for (int i = 0; i < 4; ++i) {
      int slot = t * 16 + i * 4096;
      gload_lds16(Ab + (size_t)srow[i] * 1536 + k0 * 2 + skoff[i], (char*)As + slot);
      gload_lds16(Bb + (size_t)srow[i] * 1536 + k0 * 2 + skoff[i], (char*)Bs + slot);
    }
    asm volatile("s_waitcnt vmcnt(0)" ::: "memory");
    __syncthreads();
#pragma unroll
    for (int h = 0; h < 2; ++h) {
      bf16x8 af[4], bf[4];
#pragma unroll
      for (int mi = 0; mi < 4; ++mi)
        af[mi] = *(const bf16x8*)((const char*)As + (wr + mi * 16 + cg) * 128 +
                                  (((h * 4 + g) ^ rsw) << 4));
#pragma unroll
      for (int ni = 0; ni < 4; ++ni)
        bf[ni] = *(const bf16x8*)((const char*)Bs + (wc + ni * 16 + cg) * 128 +
                                  (((h * 4 + g) ^ rsw) << 4));
#pragma unroll
      for (int mi = 0; mi < 4; ++mi)
#pragma unroll
        for (int ni = 0; ni < 4; ++ni)
          acc[mi][ni] = __builtin_amdgcn_mfma_f32_16x16x32_bf16(bf[ni], af[mi], acc[mi][ni], 0, 0, 0);
    }
  }

  const int b = (tm * 128) >> 12;
  const int nb = (tm * 128) & 4095;
#pragma unroll
  for (int mi = 0; mi < 4; ++mi)
#pragma unroll
    for (int ni = 0; ni < 4; ++ni) {
      int gcolb = tn * 128 + wc + ni * 16 + g * 4;     // quad base (4 consecutive cols)
      int s = gcolb / CDIM, hd = gcolb % CDIM;
      int h = hd >> 6, d = hd & 63;
      int n = nb + wr + mi * 16 + cg;
      if (s == 2) {
#pragma unroll
        for (int r = 0; r < 4; ++r) {
          size_t dst = 2 * PER_S + ((size_t)(b * NH + h) * DHEAD + d + r) * NSEQ + n;
          qkv[dst] = __float2bfloat16(acc[mi][ni][r]);
        }
      } else {
        uint2 o;
        o.x = pack2(acc[mi][ni][0], acc[mi][ni][1]);
        o.y = pack2(acc[mi][ni][2], acc[mi][ni][3]);
        size_t dst = (size_t)s * PER_S + ((size_t)(b * NH + h) * NSEQ + n) * DHEAD + d;
        *(uint2*)(qkv + dst) = o;
      }
    }
}

// ---------------- proj GEMM  C = A[8192,768] * B[768,768]^T + bias, 64x128 tiles
// BK=64 + same T2 swizzle. Swapped operands -> float4 C-stores. 768 blocks = 3/CU.
__global__ __launch_bounds__(256)
void gemm_proj(const __hip_bfloat16* __restrict__ A, const __hip_bfloat16* __restrict__ Bw,
               float* __restrict__ Cf, const float* __restrict__ bias) {
  __shared__ __hip_bfloat16 As[64 * 64];    // row stride 128B, swizzled
  __shared__ __hip_bfloat16 Bs[128 * 64];
  const int t = threadIdx.x;
  const int lane = t & 63, w = t >> 6, g = lane >> 4, cg = lane & 15;
  const int tm = blockIdx.x / 6, tn = blockIdx.x % 6;
  const char* Ab = (const char*)A + (size_t)tm * 64 * 768 * 2;
  const char* Bb = (const char*)Bw + (size_t)tn * 128 * 768 * 2;

  f32x4 z = {0.f, 0.f, 0.f, 0.f};
  f32x4 acc[4][2];
#pragma unroll
  for (int mi = 0; mi < 4; ++mi)
#pragma unroll
    for (int ni = 0; ni < 2; ++ni) acc[mi][ni] = z;

  const int rsw = (cg & 7);

  for (int k0 = 0; k0 < 768; k0 += 64) {
    __syncthreads();
#pragma unroll
    for (int i = 0; i < 2; ++i) {   // As: 8KB = 2 slots/thread
      int slot = t * 16 + i * 4096;
      int row = slot >> 7;
      int koff = (((slot & 127) >> 4) ^ (row & 7)) << 4;
      gload_lds16(Ab + (size_t)row * 1536 + k0 * 2 + koff, (char*)As + slot);
    }
#pragma unroll
    for (int i = 0; i < 4; ++i) {   // Bs: 16KB = 4 slots/thread
      int slot = t * 16 + i * 4096;
      int row = slot >> 7;
      int koff = (((slot & 127) >> 4) ^ (row & 7)) << 4;
      gload_lds16(Bb + (size_t)row * 1536 + k0 * 2 + koff, (char*)Bs + slot);
    }
    asm volatile("s_waitcnt vmcnt(0)" ::: "memory");
    __syncthreads();
#pragma unroll
    for (int h = 0; h < 2; ++h) {
      bf16x8 af[4], bf[2];
#pragma unroll
      for (int mi = 0; mi < 4; ++mi)
        af[mi] = *(const bf16x8*)((const char*)As + (mi * 16 + cg) * 128 +
                                  (((h * 4 + g) ^ rsw) << 4));
#pragma unroll
      for (int ni = 0; ni < 2; ++ni)
        bf[ni] = *(const bf16x8*)((const char*)Bs + (w * 32 + ni * 16 + cg) * 128 +
                                  (((h * 4 + g) ^ rsw) << 4));
#pragma unroll
      for (int mi = 0; mi < 4; ++mi)
#pragma unroll
        for (int ni = 0; ni < 2; ++ni)
          acc[mi][ni] = __builtin_amdgcn_mfma_f32_16x16x32_bf16(bf[ni], af[mi], acc[mi][ni], 0, 0, 0);
    }
  }

#pragma unroll
  for (int mi = 0; mi < 4; ++mi)
#pragma unroll
    for (int ni = 0; ni < 2; ++ni) {
      int grow = tm * 64 + mi * 16 + cg;
      int gcol = tn * 128 + w * 32 + ni * 16 + g * 4;
      float4 bv = *(const float4*)(bias + gcol);
      float4 ov;
      ov.x = acc[mi][ni][0] + bv.x;
      ov.y = acc[mi][ni][1] + bv.y;
      ov.z = acc[mi][ni][2] + bv.z;
      ov.w = acc[mi][ni][3] + bv.w;
      *(float4*)(Cf + (size_t)grow * CDIM + gcol) = ov;
    }
}

// ---------------- flash attention, swapped-operand 32x32x16, UNNORMALIZED exp2
// Round-8 proven structure (152.9 us): 2-buffer LDS K+V, __syncthreads pairs,
// vmcnt(0), setprio, hashed kv start. lsum via v_pk_add_f32 balanced tree
// (17 instrs vs 35 scalar adds; same positive-f32 pairwise-tree numerics).
struct QFrag { bf16x8 v[4]; };

static __device__ __forceinline__ void attn_tile(const char* __restrict__ Kb,
                                                 const char* __restrict__ Vb,
                                                 const QFrag& qf, int l31, int hi,
                                                 const f32x16& Z,
                                                 f32x16& o0, f32x16& o1, float& lsum) {
  const int swz = (l31 & 7) << 4;
  __builtin_amdgcn_s_setprio(1);
  bf16x8 ka = *(const bf16x8*)(Kb + l31 * 128 + ((hi * 16) ^ swz));
  bf16x8 kb = *(const bf16x8*)(Kb + (32 + l31) * 128 + ((hi * 16) ^ swz));
  f32x16 t0 = __builtin_amdgcn_mfma_f32_32x32x16_bf16(ka, qf.v[0], Z, 0, 0, 0);
  f32x16 t1 = __builtin_amdgcn_mfma_f32_32x32x16_bf16(kb, qf.v[0], Z, 0, 0, 0);
#pragma unroll
  for (int j = 1; j < 4; ++j) {
    bf16x8 kf0 = *(const bf16x8*)(Kb + l31 * 128 + ((j * 32 + hi * 16) ^ swz));
    bf16x8 kf1 = *(const bf16x8*)(Kb + (32 + l31) * 128 + ((j * 32 + hi * 16) ^ swz));
    t0 = __builtin_amdgcn_mfma_f32_32x32x16_bf16(kf0, qf.v[j], t0, 0, 0, 0);
    t1 = __builtin_amdgcn_mfma_f32_32x32x16_bf16(kf1, qf.v[j], t1, 0, 0, 0);
  }
  __builtin_amdgcn_s_setprio(0);

#pragma unroll
  for (int r = 0; r < 16; ++r) t0[r] = fexp2(t0[r]);
#pragma unroll
  for (int r = 0; r < 16; ++r) t1[r] = fexp2(t1[r]);

  // packed pairwise tree sum of the 32 P values (v_pk_add_f32; f32 throughout)
  {
    const f32x2* p0 = (const f32x2*)&t0;
    const f32x2* p1 = (const f32x2*)&t1;
    f32x2 a0 = pkadd(pkadd(p0[0], p0[1]), pkadd(p0[2], p0[3]));
    f32x2 a1 = pkadd(pkadd(p0[4], p0[5]), pkadd(p0[6], p0[7]));
    f32x2 b0 = pkadd(pkadd(p1[0], p1[1]), pkadd(p1[2], p1[3]));
    f32x2 b1 = pkadd(pkadd(p1[4], p1[5]), pkadd(p1[6], p1[7]));
    f32x2 s = pkadd(pkadd(a0, a1), pkadd(b0, b1));
    lsum += s.x + s.y;
  }

  // P -> bf16 A-frags in-register (cvt_pk pairs, permlane32_swap halves)
  uint32_t w0[8], w1[8];
#pragma unroll
  for (int i = 0; i < 8; ++i) {
    w0[i] = pack2(t0[2 * i], t0[2 * i + 1]);
    w1[i] = pack2(t1[2 * i], t1[2 * i + 1]);
  }
  permswap(w0[0], w0[2]); permswap(w0[1], w0[3]);
  permswap(w0[4], w0[6]); permswap(w0[5], w0[7]);
  permswap(w1[0], w1[2]); permswap(w1[1], w1[3]);
  permswap(w1[4], w1[6]); permswap(w1[5], w1[7]);
  union { u32x4 u; bf16x8 b; } pa[4];
  pa[0].u = (u32x4){w0[0], w0[1], w0[2], w0[3]};
  pa[1].u = (u32x4){w0[4], w0[5], w0[6], w0[7]};
  pa[2].u = (u32x4){w1[0], w1[1], w1[2], w1[3]};
  pa[3].u = (u32x4){w1[4], w1[5], w1[6], w1[7]};

  // O += P V   (A = P-frag, B = V^T-frag from LDS)
  __builtin_amdgcn_s_setprio(1);
#pragma unroll
  for (int s = 0; s < 2; ++s)
#pragma unroll
    for (int j = 0; j < 2; ++j) {
      bf16x8 vf0 = *(const bf16x8*)(Vb + l31 * 128 + ((s * 64 + j * 32 + hi * 16) ^ swz));
      bf16x8 vf1 = *(const bf16x8*)(Vb + (32 + l31) * 128 + ((s * 64 + j * 32 + hi * 16) ^ swz));
      o0 = __builtin_amdgcn_mfma_f32_32x32x16_bf16(pa[s * 2 + j].b, vf0, o0, 0, 0, 0);
      o1 = __builtin_amdgcn_mfma_f32_32x32x16_bf16(pa[s * 2 + j].b, vf1, o1, 0, 0, 0);
    }
  __builtin_amdgcn_s_setprio(0);
}

__global__ __launch_bounds__(256)
void attn_kernel(const __hip_bfloat16* __restrict__ Qg,   // [bh][n][d]
                 const __hip_bfloat16* __restrict__ Kg,   // [bh][n][d]
                 const __hip_bfloat16* __restrict__ Vtg,  // [bh][d][n]
                 __hip_bfloat16* __restrict__ Og) {
  __shared__ char Ks[2][8192];
  __shared__ char Vs[2][8192];

  const int t = threadIdx.x;
  const int lane = t & 63, w = t >> 6;
  const int l31 = lane & 31, hi = lane >> 5;

  // bijective XCD swizzle: 768 blocks, 96/XCD -> each XCD owns 3 whole heads
  const int wg = (blockIdx.x & 7) * 96 + (blockIdx.x >> 3);
  const int bh = wg >> 5, qblk = wg & 31;
  // de-phase-lock co-resident blocks: hashed kv start tile (sum is order-invariant)
  const int start = (int)((wg * 2654435761u) >> 26) & 63;

  const char* Qb = (const char*)Qg + (size_t)bh * (NSEQ * DHEAD * 2);
  const char* Kb = (const char*)Kg + (size_t)bh * (NSEQ * DHEAD * 2);
  const char* Vb = (const char*)Vtg + (size_t)bh * (NSEQ * DHEAD * 2);

  // staging map: LDS slot p -> row=p>>7, col=(p&127); global src col pre-swizzled (m173)
  const int s0 = t * 16, s1 = t * 16 + 4096;
  const int r0 = s0 >> 7, c0 = (s0 & 127) ^ ((r0 & 7) << 4);
  const int r1 = s1 >> 7, c1 = (s1 & 127) ^ ((r1 & 7) << 4);
  const char* ks0 = Kb + r0 * 128 + c0;
  const char* ks1 = Kb + r1 * 128 + c1;
  const char* vs0 = Vb + (size_t)r0 * (NSEQ * 2) + c0;
  const char* vs1 = Vb + (size_t)r1 * (NSEQ * 2) + c1;

#define STAGE(buf, tile)                                            \
  do {                                                              \
    int kv0_ = (tile)*64;                                           \
    gload_lds16(ks0 + (size_t)kv0_ * 128, &Ks[buf][s0]);            \
    gload_lds16(ks1 + (size_t)kv0_ * 128, &Ks[buf][s1]);            \
    gload_lds16(vs0 + kv0_ * 2, &Vs[buf][s0]);                      \
    gload_lds16(vs1 + kv0_ * 2, &Vs[buf][s1]);                      \
  } while (0)

  // Q fragments (B-operand: n=q at lane&31, k=d slice at hi*16), 4 d-slices
  const int q0 = qblk * 128 + w * 32;
  QFrag qf;
#pragma unroll
  for (int j = 0; j < 4; ++j)
    qf.v[j] = *(const bf16x8*)(Qb + (size_t)(q0 + l31) * 128 + j * 32 + hi * 16);

  f32x16 o0, o1, Z;
#pragma unroll
  for (int r = 0; r < 16; ++r) { o0[r] = 0.f; o1[r] = 0.f; Z[r] = 0.f; }
  float lsum = 0.f;

  STAGE(0, start);
  asm volatile("s_waitcnt vmcnt(0)" ::: "memory");
  __syncthreads();

  for (int i = 0; i < 64; i += 2) {
    STAGE(1, (i + 1 + start) & 63);
    attn_tile(Ks[0], Vs[0], qf, l31, hi, Z, o0, o1, lsum);
    asm volatile("s_waitcnt vmcnt(0)" ::: "memory");
    __syncthreads();
    if (i + 2 < 64) STAGE(0, (i + 2 + start) & 63);
    attn_tile(Ks[1], Vs[1], qf, l31, hi, Z, o0, o1, lsum);
    asm volatile("s_waitcnt vmcnt(0)" ::: "memory");
    __syncthreads();
  }

  // epilogue: cross-half l combine (once per block), then divide + store
  {
    uint32_t c = __builtin_bit_cast(uint32_t, lsum), d = c;
    permswap(c, d);
    lsum = __builtin_bit_cast(float, c) + __builtin_bit_cast(float, d);
  }
  float linv = 1.0f / lsum;
  const int b = bh / NH, h = bh % NH;
#pragma unroll
  for (int r = 0; r < 16; ++r) {
    int ql = (r & 3) + 8 * (r >> 2) + 4 * hi;
    float lr = __shfl(linv, ql, 32);
    size_t base = (size_t)(b * NSEQ + q0 + ql) * CDIM + h * DHEAD;
    Og[base + l31] = __float2bfloat16(o0[r] * lr);
    Og[base + 32 + l31] = __float2bfloat16(o1[r] * lr);
  }
#undef STAGE
}

extern "C" void kernel_launch(void* const* d_in, const int* in_sizes, int n_in,
                              void* d_out, int out_size, void* d_ws, size_t ws_size,
                              hipStream_t stream) {
  const float* x = (const float*)d_in[0];
  const float* wqkv = (const float*)d_in[1];
  const float* wproj = (const float*)d_in[2];
  const float* bproj = (const float*)d_in[3];

  char* ws = (char*)d_ws;
  __hip_bfloat16* xb     = (__hip_bfloat16*)(ws);              // 12,582,912 B
  __hip_bfloat16* wqkvb  = (__hip_bfloat16*)(ws + 12582912);   //  3,538,944 B
  __hip_bfloat16* wprojb = (__hip_bfloat16*)(ws + 16121856);   //  1,179,648 B
  __hip_bfloat16* qkvws  = (__hip_bfloat16*)(ws + 17301504);   // 37,748,736 B
  __hip_bfloat16* attnws = (__hip_bfloat16*)(ws + 55050240);   // 12,582,912 B

  const float QSCALE = 0.125f * 1.44269504088896340736f;  // head_dim^-0.5 * log2(e)

  cvt_all<<<8448, 256, 0, stream>>>(x, wqkv, wproj, xb, QSCALE);

  gemm_qkv<<<64 * 18, 256, 0, stream>>>(xb, wqkvb, qkvws);

  attn_kernel<<<768, 256, 0, stream>>>(qkvws, qkvws + PER_S, qkvws + 2 * PER_S, attnws);

  gemm_proj<<<128 * 6, 256, 0, stream>>>(attnws, wprojb, (float*)d_out, bproj);
}

// Round 17
// 229.605 us; speedup vs baseline: 1.0242x; 1.0056x over previous
//
#include <hip/hip_runtime.h>
#include <hip/hip_bf16.h>
#include <stdint.h>

// Attention_9234179687676: x[2,4096,768] -> qkv -> 12-head attn (N=4096, D=64) -> proj+bias
// fp32 in/out, bf16 MFMA internally.

typedef short bf16x8 __attribute__((ext_vector_type(8)));
typedef float f32x4 __attribute__((ext_vector_type(4)));
typedef float f32x16 __attribute__((ext_vector_type(16)));
typedef uint32_t u32x4 __attribute__((ext_vector_type(4)));

#define B_SZ 2
#define NSEQ 4096
#define CDIM 768
#define NH 12
#define DHEAD 64
#define PER_S ((size_t)8192 * 768)

static __device__ __forceinline__ void gload_lds16(const void* g, void* l) {
  __builtin_amdgcn_global_load_lds(
      (const __attribute__((address_space(1))) uint32_t*)g,
      (__attribute__((address_space(3))) uint32_t*)l, 16, 0, 0);
}

// packed f32->bf16 (RNE): 1 instruction for 2 values
static __device__ __forceinline__ uint32_t pack2(float lo, float hi) {
  uint32_t r;
  asm("v_cvt_pk_bf16_f32 %0, %1, %2" : "=v"(r) : "v"(lo), "v"(hi));
  return r;
}

static __device__ __forceinline__ float fexp2(float x) {
#if __has_builtin(__builtin_amdgcn_exp2f)
  return __builtin_amdgcn_exp2f(x);   // raw v_exp_f32
#else
  return exp2f(x);
#endif
}

static __device__ __forceinline__ void permswap(uint32_t& a, uint32_t& b) {
#if __has_builtin(__builtin_amdgcn_permlane32_swap)
  auto r = __builtin_amdgcn_permlane32_swap((int)a, (int)b, false, false);
  a = (uint32_t)r[0];
  b = (uint32_t)r[1];
#else
  asm volatile("v_permlane32_swap_b32 %0, %1" : "+v"(a), "+v"(b));
#endif
}

// ---------------- single fused fp32 -> bf16 convert into contiguous ws region
// regions (float4 units): x [0,1572864) ; wqkv [1572864,2015232) with QSCALE on
// its first 147456 (= 768 Q rows x 768 / 4); wproj [2015232,2162688)
__global__ void cvt_all(const float* __restrict__ x, const float* __restrict__ wqkv,
                        const float* __restrict__ wproj, __hip_bfloat16* __restrict__ dst,
                        float qscale) {
  int i = blockIdx.x * 256 + threadIdx.x;
  if (i >= 2162688) return;
  const float* src;
  int off;
  float sc = 1.0f;
  if (i < 1572864) {
    src = x; off = 0;
  } else if (i < 2015232) {
    src = wqkv; off = 1572864;
    if (i < 1572864 + 147456) sc = qscale;
  } else {
    src = wproj; off = 2015232;
  }
  float4 v = ((const float4*)src)[i - off];
  uint2 o;
  o.x = pack2(v.x * sc, v.y * sc);
  o.y = pack2(v.z * sc, v.w * sc);
  ((uint2*)dst)[i] = o;
}

// ---------------- QKV GEMM  C = A[8192,768] * B[2304,768]^T, 128x128 tiles
// BK=64 (12 barrier periods) + T2 XOR-swizzled LDS (16B unit ^ row&7,
// pre-swizzled on the GLOBAL source, linear LDS dest - m173 pattern).
// MFMA operands swapped (mfma(bf,af)): reg-quad spans 4 consecutive gcols.
__global__ __launch_bounds__(256)
void gemm_qkv(const __hip_bfloat16* __restrict__ A, const __hip_bfloat16* __restrict__ Bw,
              __hip_bfloat16* __restrict__ qkv) {
  __shared__ __hip_bfloat16 As[128 * 64];   // row stride 128B, swizzled
  __shared__ __hip_bfloat16 Bs[128 * 64];
  const int t = threadIdx.x;
  const int lane = t & 63, w = t >> 6, g = lane >> 4, cg = lane & 15;
  const int wr = (w >> 1) * 64, wc = (w & 1) * 64;
  const int tm = blockIdx.x / 18, tn = blockIdx.x % 18;
  const char* Ab = (const char*)A + (size_t)tm * 128 * 768 * 2;
  const char* Bb = (const char*)Bw + (size_t)tn * 128 * 768 * 2;

  f32x4 z = {0.f, 0.f, 0.f, 0.f};
  f32x4 acc[4][4];
#pragma unroll
  for (int mi = 0; mi < 4; ++mi)
#pragma unroll
    for (int ni = 0; ni < 4; ++ni) acc[mi][ni] = z;

  // staging map (per gload slot): row = slot>>7, 16B-unit p = (slot&127)>>4;
  // source k-unit = p ^ (row&7)  -> LDS linear, reads use the same XOR.
  int srow[4], skoff[4];
#pragma unroll
  for (int i = 0; i < 4; ++i) {
    int slot = t * 16 + i * 4096;
    srow[i] = slot >> 7;
    skoff[i] = (((slot & 127) >> 4) ^ (srow[i] & 7)) << 4;
  }
  const int rsw = (cg & 7);

  for (int k0 = 0; k0 < 768; k0 += 64) {
    __syncthreads();
#pragma unroll
    for (int i = 0; i < 4; ++i) {
      int slot = t * 16 + i * 4096;
      gload_lds16(Ab + (size_t)srow[i] * 1536 + k0 * 2 + skoff[i], (char*)As + slot);
      gload_lds16(Bb + (size_t)srow[i] * 1536 + k0 * 2 + skoff[i], (char*)Bs + slot);
    }
    asm volatile("s_waitcnt vmcnt(0)" ::: "memory");
    __syncthreads();
#pragma unroll
    for (int h = 0; h < 2; ++h) {
      bf16x8 af[4], bf[4];
#pragma unroll
      for (int mi = 0; mi < 4; ++mi)
        af[mi] = *(const bf16x8*)((const char*)As + (wr + mi * 16 + cg) * 128 +
                                  (((h * 4 + g) ^ rsw) << 4));
#pragma unroll
      for (int ni = 0; ni < 4; ++ni)
        bf[ni] = *(const bf16x8*)((const char*)Bs + (wc + ni * 16 + cg) * 128 +
                                  (((h * 4 + g) ^ rsw) << 4));
#pragma unroll
      for (int mi = 0; mi < 4; ++mi)
#pragma unroll
        for (int ni = 0; ni < 4; ++ni)
          acc[mi][ni] = __builtin_amdgcn_mfma_f32_16x16x32_bf16(bf[ni], af[mi], acc[mi][ni], 0, 0, 0);
    }
  }

  const int b = (tm * 128) >> 12;
  const int nb = (tm * 128) & 4095;
#pragma unroll
  for (int mi = 0; mi < 4; ++mi)
#pragma unroll
    for (int ni = 0; ni < 4; ++ni) {
      int gcolb = tn * 128 + wc + ni * 16 + g * 4;     // quad base (4 consecutive cols)
      int s = gcolb / CDIM, hd = gcolb % CDIM;
      int h = hd >> 6, d = hd & 63;
      int n = nb + wr + mi * 16 + cg;
      if (s == 2) {
#pragma unroll
        for (int r = 0; r < 4; ++r) {
          size_t dst = 2 * PER_S + ((size_t)(b * NH + h) * DHEAD + d + r) * NSEQ + n;
          qkv[dst] = __float2bfloat16(acc[mi][ni][r]);
        }
      } else {
        uint2 o;
        o.x = pack2(acc[mi][ni][0], acc[mi][ni][1]);
        o.y = pack2(acc[mi][ni][2], acc[mi][ni][3]);
        size_t dst = (size_t)s * PER_S + ((size_t)(b * NH + h) * NSEQ + n) * DHEAD + d;
        *(uint2*)(qkv + dst) = o;
      }
    }
}

// ---------------- proj GEMM  C = A[8192,768] * B[768,768]^T + bias, 64x128 tiles
// BK=64 + same T2 swizzle. Swapped operands -> float4 C-stores. 768 blocks = 3/CU.
__global__ __launch_bounds__(256)
void gemm_proj(const __hip_bfloat16* __restrict__ A, const __hip_bfloat16* __restrict__ Bw,
               float* __restrict__ Cf, const float* __restrict__ bias) {
  __shared__ __hip_bfloat16 As[64 * 64];    // row stride 128B, swizzled
  __shared__ __hip_bfloat16 Bs[128 * 64];
  const int t = threadIdx.x;
  const int lane = t & 63, w = t >> 6, g = lane >> 4, cg = lane & 15;
  const int tm = blockIdx.x / 6, tn = blockIdx.x % 6;
  const char* Ab = (const char*)A + (size_t)tm * 64 * 768 * 2;
  const char* Bb = (const char*)Bw + (size_t)tn * 128 * 768 * 2;

  f32x4 z = {0.f, 0.f, 0.f, 0.f};
  f32x4 acc[4][2];
#pragma unroll
  for (int mi = 0; mi < 4; ++mi)
#pragma unroll
    for (int ni = 0; ni < 2; ++ni) acc[mi][ni] = z;

  const int rsw = (cg & 7);

  for (int k0 = 0; k0 < 768; k0 += 64) {
    __syncthreads();
#pragma unroll
    for (int i = 0; i < 2; ++i) {   // As: 8KB = 2 slots/thread
      int slot = t * 16 + i * 4096;
      int row = slot >> 7;
      int koff = (((slot & 127) >> 4) ^ (row & 7)) << 4;
      gload_lds16(Ab + (size_t)row * 1536 + k0 * 2 + koff, (char*)As + slot);
    }
#pragma unroll
    for (int i = 0; i < 4; ++i) {   // Bs: 16KB = 4 slots/thread
      int slot = t * 16 + i * 4096;
      int row = slot >> 7;
      int koff = (((slot & 127) >> 4) ^ (row & 7)) << 4;
      gload_lds16(Bb + (size_t)row * 1536 + k0 * 2 + koff, (char*)Bs + slot);
    }
    asm volatile("s_waitcnt vmcnt(0)" ::: "memory");
    __syncthreads();
#pragma unroll
    for (int h = 0; h < 2; ++h) {
      bf16x8 af[4], bf[2];
#pragma unroll
      for (int mi = 0; mi < 4; ++mi)
        af[mi] = *(const bf16x8*)((const char*)As + (mi * 16 + cg) * 128 +
                                  (((h * 4 + g) ^ rsw) << 4));
#pragma unroll
      for (int ni = 0; ni < 2; ++ni)
        bf[ni] = *(const bf16x8*)((const char*)Bs + (w * 32 + ni * 16 + cg) * 128 +
                                  (((h * 4 + g) ^ rsw) << 4));
#pragma unroll
      for (int mi = 0; mi < 4; ++mi)
#pragma unroll
        for (int ni = 0; ni < 2; ++ni)
          acc[mi][ni] = __builtin_amdgcn_mfma_f32_16x16x32_bf16(bf[ni], af[mi], acc[mi][ni], 0, 0, 0);
    }
  }

#pragma unroll
  for (int mi = 0; mi < 4; ++mi)
#pragma unroll
    for (int ni = 0; ni < 2; ++ni) {
      int grow = tm * 64 + mi * 16 + cg;
      int gcol = tn * 128 + w * 32 + ni * 16 + g * 4;
      float4 bv = *(const float4*)(bias + gcol);
      float4 ov;
      ov.x = acc[mi][ni][0] + bv.x;
      ov.y = acc[mi][ni][1] + bv.y;
      ov.z = acc[mi][ni][2] + bv.z;
      ov.w = acc[mi][ni][3] + bv.w;
      *(float4*)(Cf + (size_t)grow * CDIM + gcol) = ov;
    }
}

// ---------------- flash attention, swapped-operand 32x32x16, UNNORMALIZED exp2
// Round-8 proven structure (152.9 us): 2-buffer LDS K+V, __syncthreads pairs,
// vmcnt(0), setprio, hashed kv start, f32 tree-sum denominator.
struct QFrag { bf16x8 v[4]; };

static __device__ __forceinline__ void attn_tile(const char* __restrict__ Kb,
                                                 const char* __restrict__ Vb,
                                                 const QFrag& qf, int l31, int hi,
                                                 const f32x16& Z,
                                                 f32x16& o0, f32x16& o1, float& lsum) {
  const int swz = (l31 & 7) << 4;
  __builtin_amdgcn_s_setprio(1);
  bf16x8 ka = *(const bf16x8*)(Kb + l31 * 128 + ((hi * 16) ^ swz));
  bf16x8 kb = *(const bf16x8*)(Kb + (32 + l31) * 128 + ((hi * 16) ^ swz));
  f32x16 t0 = __builtin_amdgcn_mfma_f32_32x32x16_bf16(ka, qf.v[0], Z, 0, 0, 0);
  f32x16 t1 = __builtin_amdgcn_mfma_f32_32x32x16_bf16(kb, qf.v[0], Z, 0, 0, 0);
#pragma unroll
  for (int j = 1; j < 4; ++j) {
    bf16x8 kf0 = *(const bf16x8*)(Kb + l31 * 128 + ((j * 32 + hi * 16) ^ swz));
    bf16x8 kf1 = *(const bf16x8*)(Kb + (32 + l31) * 128 + ((j * 32 + hi * 16) ^ swz));
    t0 = __builtin_amdgcn_mfma_f32_32x32x16_bf16(kf0, qf.v[j], t0, 0, 0, 0);
    t1 = __builtin_amdgcn_mfma_f32_32x32x16_bf16(kf1, qf.v[j], t1, 0, 0, 0);
  }
  __builtin_amdgcn_s_setprio(0);

#pragma unroll
  for (int r = 0; r < 16; ++r) t0[r] = fexp2(t0[r]);
#pragma unroll
  for (int r = 0; r < 16; ++r) t1[r] = fexp2(t1[r]);

  // pairwise tree sum of own 32 kv (f32 P); cross-half combine deferred to epilogue
  float s0 = ((t0[0] + t0[1]) + (t0[2] + t0[3])) + ((t0[4] + t0[5]) + (t0[6] + t0[7]));
  float s1 = ((t0[8] + t0[9]) + (t0[10] + t0[11])) + ((t0[12] + t0[13]) + (t0[14] + t0[15]));
  float s2 = ((t1[0] + t1[1]) + (t1[2] + t1[3])) + ((t1[4] + t1[5]) + (t1[6] + t1[7]));
  float s3 = ((t1[8] + t1[9]) + (t1[10] + t1[11])) + ((t1[12] + t1[13]) + (t1[14] + t1[15]));
  lsum += (s0 + s1) + (s2 + s3);

  // P -> bf16 A-frags in-register (cvt_pk pairs, permlane32_swap halves)
  uint32_t w0[8], w1[8];
#pragma unroll
  for (int i = 0; i < 8; ++i) {
    w0[i] = pack2(t0[2 * i], t0[2 * i + 1]);
    w1[i] = pack2(t1[2 * i], t1[2 * i + 1]);
  }
  permswap(w0[0], w0[2]); permswap(w0[1], w0[3]);
  permswap(w0[4], w0[6]); permswap(w0[5], w0[7]);
  permswap(w1[0], w1[2]); permswap(w1[1], w1[3]);
  permswap(w1[4], w1[6]); permswap(w1[5], w1[7]);
  union { u32x4 u; bf16x8 b; } pa[4];
  pa[0].u = (u32x4){w0[0], w0[1], w0[2], w0[3]};
  pa[1].u = (u32x4){w0[4], w0[5], w0[6], w0[7]};
  pa[2].u = (u32x4){w1[0], w1[1], w1[2], w1[3]};
  pa[3].u = (u32x4){w1[4], w1[5], w1[6], w1[7]};

  // O += P V   (A = P-frag, B = V^T-frag from LDS)
  __builtin_amdgcn_s_setprio(1);
#pragma unroll
  for (int s = 0; s < 2; ++s)
#pragma unroll
    for (int j = 0; j < 2; ++j) {
      bf16x8 vf0 = *(const bf16x8*)(Vb + l31 * 128 + ((s * 64 + j * 32 + hi * 16) ^ swz));
      bf16x8 vf1 = *(const bf16x8*)(Vb + (32 + l31) * 128 + ((s * 64 + j * 32 + hi * 16) ^ swz));
      o0 = __builtin_amdgcn_mfma_f32_32x32x16_bf16(pa[s * 2 + j].b, vf0, o0, 0, 0, 0);
      o1 = __builtin_amdgcn_mfma_f32_32x32x16_bf16(pa[s * 2 + j].b, vf1, o1, 0, 0, 0);
    }
  __builtin_amdgcn_s_setprio(0);
}

__global__ __launch_bounds__(256)
void attn_kernel(const __hip_bfloat16* __restrict__ Qg,   // [bh][n][d]
                 const __hip_bfloat16* __restrict__ Kg,   // [bh][n][d]
                 const __hip_bfloat16* __restrict__ Vtg,  // [bh][d][n]
                 __hip_bfloat16* __restrict__ Og) {
  __shared__ char Ks[2][8192];
  __shared__ char Vs[2][8192];

  const int t = threadIdx.x;
  const int lane = t & 63, w = t >> 6;
  const int l31 = lane & 31, hi = lane >> 5;

  // bijective XCD swizzle: 768 blocks, 96/XCD -> each XCD owns 3 whole heads
  const int wg = (blockIdx.x & 7) * 96 + (blockIdx.x >> 3);
  const int bh = wg >> 5, qblk = wg & 31;
  // de-phase-lock co-resident blocks: hashed kv start tile (sum is order-invariant)
  const int start = (int)((wg * 2654435761u) >> 26) & 63;

  const char* Qb = (const char*)Qg + (size_t)bh * (NSEQ * DHEAD * 2);
  const char* Kb = (const char*)Kg + (size_t)bh * (NSEQ * DHEAD * 2);
  const char* Vb = (const char*)Vtg + (size_t)bh * (NSEQ * DHEAD * 2);

  // staging map: LDS slot p -> row=p>>7, col=(p&127); global src col pre-swizzled (m173)
  const int s0 = t * 16, s1 = t * 16 + 4096;
  const int r0 = s0 >> 7, c0 = (s0 & 127) ^ ((r0 & 7) << 4);
  const int r1 = s1 >> 7, c1 = (s1 & 127) ^ ((r1 & 7) << 4);
  const char* ks0 = Kb + r0 * 128 + c0;
  const char* ks1 = Kb + r1 * 128 + c1;
  const char* vs0 = Vb + (size_t)r0 * (NSEQ * 2) + c0;
  const char* vs1 = Vb + (size_t)r1 * (NSEQ * 2) + c1;

#define STAGE(buf, tile)                                            \
  do {                                                              \
    int kv0_ = (tile)*64;                                           \
    gload_lds16(ks0 + (size_t)kv0_ * 128, &Ks[buf][s0]);            \
    gload_lds16(ks1 + (size_t)kv0_ * 128, &Ks[buf][s1]);            \
    gload_lds16(vs0 + kv0_ * 2, &Vs[buf][s0]);                      \
    gload_lds16(vs1 + kv0_ * 2, &Vs[buf][s1]);                      \
  } while (0)

  // Q fragments (B-operand: n=q at lane&31, k=d slice at hi*16), 4 d-slices
  const int q0 = qblk * 128 + w * 32;
  QFrag qf;
#pragma unroll
  for (int j = 0; j < 4; ++j)
    qf.v[j] = *(const bf16x8*)(Qb + (size_t)(q0 + l31) * 128 + j * 32 + hi * 16);

  f32x16 o0, o1, Z;
#pragma unroll
  for (int r = 0; r < 16; ++r) { o0[r] = 0.f; o1[r] = 0.f; Z[r] = 0.f; }
  float lsum = 0.f;

  STAGE(0, start);
  asm volatile("s_waitcnt vmcnt(0)" ::: "memory");
  __syncthreads();

  for (int i = 0; i < 64; i += 2) {
    STAGE(1, (i + 1 + start) & 63);
    attn_tile(Ks[0], Vs[0], qf, l31, hi, Z, o0, o1, lsum);
    asm volatile("s_waitcnt vmcnt(0)" ::: "memory");
    __syncthreads();
    if (i + 2 < 64) STAGE(0, (i + 2 + start) & 63);
    attn_tile(Ks[1], Vs[1], qf, l31, hi, Z, o0, o1, lsum);
    asm volatile("s_waitcnt vmcnt(0)" ::: "memory");
    __syncthreads();
  }

  // epilogue: cross-half l combine (once per block), then divide + store
  {
    uint32_t c = __builtin_bit_cast(uint32_t, lsum), d = c;
    permswap(c, d);
    lsum = __builtin_bit_cast(float, c) + __builtin_bit_cast(float, d);
  }
  float linv = 1.0f / lsum;
  const int b = bh / NH, h = bh % NH;
#pragma unroll
  for (int r = 0; r < 16; ++r) {
    int ql = (r & 3) + 8 * (r >> 2) + 4 * hi;
    float lr = __shfl(linv, ql, 32);
    size_t base = (size_t)(b * NSEQ + q0 + ql) * CDIM + h * DHEAD;
    Og[base + l31] = __float2bfloat16(o0[r] * lr);
    Og[base + 32 + l31] = __float2bfloat16(o1[r] * lr);
  }
#undef STAGE
}

extern "C" void kernel_launch(void* const* d_in, const int* in_sizes, int n_in,
                              void* d_out, int out_size, void* d_ws, size_t ws_size,
                              hipStream_t stream) {
  const float* x = (const float*)d_in[0];
  const float* wqkv = (const float*)d_in[1];
  const float* wproj = (const float*)d_in[2];
  const float* bproj = (const float*)d_in[3];

  char* ws = (char*)d_ws;
  __hip_bfloat16* xb     = (__hip_bfloat16*)(ws);              // 12,582,912 B
  __hip_bfloat16* wqkvb  = (__hip_bfloat16*)(ws + 12582912);   //  3,538,944 B
  __hip_bfloat16* wprojb = (__hip_bfloat16*)(ws + 16121856);   //  1,179,648 B
  __hip_bfloat16* qkvws  = (__hip_bfloat16*)(ws + 17301504);   // 37,748,736 B
  __hip_bfloat16* attnws = (__hip_bfloat16*)(ws + 55050240);   // 12,582,912 B

  const float QSCALE = 0.125f * 1.44269504088896340736f;  // head_dim^-0.5 * log2(e)

  cvt_all<<<8448, 256, 0, stream>>>(x, wqkv, wproj, xb, QSCALE);

  gemm_qkv<<<64 * 18, 256, 0, stream>>>(xb, wqkvb, qkvws);

  attn_kernel<<<768, 256, 0, stream>>>(qkvws, qkvws + PER_S, qkvws + 2 * PER_S, attnws);

  gemm_proj<<<128 * 6, 256, 0, stream>>>(attnws, wprojb, (float*)d_out, bproj);
}

// Round 18
// 225.211 us; speedup vs baseline: 1.0442x; 1.0195x over previous
//
#include <hip/hip_runtime.h>
#include <hip/hip_bf16.h>
#include <stdint.h>

// Attention_9234179687676: x[2,4096,768] -> qkv -> 12-head attn (N=4096, D=64) -> proj+bias
// fp32 in/out, bf16 MFMA internally.

typedef short bf16x8 __attribute__((ext_vector_type(8)));
typedef float f32x4 __attribute__((ext_vector_type(4)));
typedef float f32x16 __attribute__((ext_vector_type(16)));
typedef uint32_t u32x4 __attribute__((ext_vector_type(4)));

#define B_SZ 2
#define NSEQ 4096
#define CDIM 768
#define NH 12
#define DHEAD 64
#define PER_S ((size_t)8192 * 768)

static __device__ __forceinline__ void gload_lds16(const void* g, void* l) {
  __builtin_amdgcn_global_load_lds(
      (const __attribute__((address_space(1))) uint32_t*)g,
      (__attribute__((address_space(3))) uint32_t*)l, 16, 0, 0);
}

// packed f32->bf16 (RNE): 1 instruction for 2 values
static __device__ __forceinline__ uint32_t pack2(float lo, float hi) {
  uint32_t r;
  asm("v_cvt_pk_bf16_f32 %0, %1, %2" : "=v"(r) : "v"(lo), "v"(hi));
  return r;
}

static __device__ __forceinline__ float fexp2(float x) {
#if __has_builtin(__builtin_amdgcn_exp2f)
  return __builtin_amdgcn_exp2f(x);   // raw v_exp_f32
#else
  return exp2f(x);
#endif
}

static __device__ __forceinline__ void permswap(uint32_t& a, uint32_t& b) {
#if __has_builtin(__builtin_amdgcn_permlane32_swap)
  auto r = __builtin_amdgcn_permlane32_swap((int)a, (int)b, false, false);
  a = (uint32_t)r[0];
  b = (uint32_t)r[1];
#else
  asm volatile("v_permlane32_swap_b32 %0, %1" : "+v"(a), "+v"(b));
#endif
}

// ---------------- single fused fp32 -> bf16 convert into contiguous ws region
// regions (float4 units): x [0,1572864) ; wqkv [1572864,2015232) with QSCALE on
// its first 147456 (= 768 Q rows x 768 / 4); wproj [2015232,2162688)
__global__ void cvt_all(const float* __restrict__ x, const float* __restrict__ wqkv,
                        const float* __restrict__ wproj, __hip_bfloat16* __restrict__ dst,
                        float qscale) {
  int i = blockIdx.x * 256 + threadIdx.x;
  if (i >= 2162688) return;
  const float* src;
  int off;
  float sc = 1.0f;
  if (i < 1572864) {
    src = x; off = 0;
  } else if (i < 2015232) {
    src = wqkv; off = 1572864;
    if (i < 1572864 + 147456) sc = qscale;
  } else {
    src = wproj; off = 2015232;
  }
  float4 v = ((const float4*)src)[i - off];
  uint2 o;
  o.x = pack2(v.x * sc, v.y * sc);
  o.y = pack2(v.z * sc, v.w * sc);
  ((uint2*)dst)[i] = o;
}

// ---------------- QKV GEMM  C = A[8192,768] * B[2304,768]^T, 128x128 tiles
// BK=64 + T2 XOR-swizzled LDS + XCD-aware block swizzle (T1): 1152 = 8x144
// blocks; each XCD owns 8 contiguous tm-panels x all tn -> A slice (1.6MB) +
// B (3.5MB) are L2-resident, killing the 18x A re-fetch from HBM.
// MFMA operands swapped (mfma(bf,af)): reg-quad spans 4 consecutive gcols.
__global__ __launch_bounds__(256)
void gemm_qkv(const __hip_bfloat16* __restrict__ A, const __hip_bfloat16* __restrict__ Bw,
              __hip_bfloat16* __restrict__ qkv) {
  __shared__ __hip_bfloat16 As[128 * 64];   // row stride 128B, swizzled
  __shared__ __hip_bfloat16 Bs[128 * 64];
  const int t = threadIdx.x;
  const int lane = t & 63, w = t >> 6, g = lane >> 4, cg = lane & 15;
  const int wr = (w >> 1) * 64, wc = (w & 1) * 64;
  // bijective XCD swizzle: 1152 blocks = 8 XCDs x 144
  const int wgq = (blockIdx.x & 7) * 144 + (blockIdx.x >> 3);
  const int tm = wgq / 18, tn = wgq % 18;
  const char* Ab = (const char*)A + (size_t)tm * 128 * 768 * 2;
  const char* Bb = (const char*)Bw + (size_t)tn * 128 * 768 * 2;

  f32x4 z = {0.f, 0.f, 0.f, 0.f};
  f32x4 acc[4][4];
#pragma unroll
  for (int mi = 0; mi < 4; ++mi)
#pragma unroll
    for (int ni = 0; ni < 4; ++ni) acc[mi][ni] = z;

  // staging map (per gload slot): row = slot>>7, 16B-unit p = (slot&127)>>4;
  // source k-unit = p ^ (row&7)  -> LDS linear, reads use the same XOR.
  int srow[4], skoff[4];
#pragma unroll
  for (int i = 0; i < 4; ++i) {
    int slot = t * 16 + i * 4096;
    srow[i] = slot >> 7;
    skoff[i] = (((slot & 127) >> 4) ^ (srow[i] & 7)) << 4;
  }
  const int rsw = (cg & 7);

  for (int k0 = 0; k0 < 768; k0 += 64) {
    __syncthreads();
#pragma unroll
    for (int i = 0; i < 4; ++i) {
      int slot = t * 16 + i * 4096;
      gload_lds16(Ab + (size_t)srow[i] * 1536 + k0 * 2 + skoff[i], (char*)As + slot);
      gload_lds16(Bb + (size_t)srow[i] * 1536 + k0 * 2 + skoff[i], (char*)Bs + slot);
    }
    asm volatile("s_waitcnt vmcnt(0)" ::: "memory");
    __syncthreads();
#pragma unroll
    for (int h = 0; h < 2; ++h) {
      bf16x8 af[4], bf[4];
#pragma unroll
      for (int mi = 0; mi < 4; ++mi)
        af[mi] = *(const bf16x8*)((const char*)As + (wr + mi * 16 + cg) * 128 +
                                  (((h * 4 + g) ^ rsw) << 4));
#pragma unroll
      for (int ni = 0; ni < 4; ++ni)
        bf[ni] = *(const bf16x8*)((const char*)Bs + (wc + ni * 16 + cg) * 128 +
                                  (((h * 4 + g) ^ rsw) << 4));
#pragma unroll
      for (int mi = 0; mi < 4; ++mi)
#pragma unroll
        for (int ni = 0; ni < 4; ++ni)
          acc[mi][ni] = __builtin_amdgcn_mfma_f32_16x16x32_bf16(bf[ni], af[mi], acc[mi][ni], 0, 0, 0);
    }
  }

  const int b = (tm * 128) >> 12;
  const int nb = (tm * 128) & 4095;
#pragma unroll
  for (int mi = 0; mi < 4; ++mi)
#pragma unroll
    for (int ni = 0; ni < 4; ++ni) {
      int gcolb = tn * 128 + wc + ni * 16 + g * 4;     // quad base (4 consecutive cols)
      int s = gcolb / CDIM, hd = gcolb % CDIM;
      int h = hd >> 6, d = hd & 63;
      int n = nb + wr + mi * 16 + cg;
      if (s == 2) {
#pragma unroll
        for (int r = 0; r < 4; ++r) {
          size_t dst = 2 * PER_S + ((size_t)(b * NH + h) * DHEAD + d + r) * NSEQ + n;
          qkv[dst] = __float2bfloat16(acc[mi][ni][r]);
        }
      } else {
        uint2 o;
        o.x = pack2(acc[mi][ni][0], acc[mi][ni][1]);
        o.y = pack2(acc[mi][ni][2], acc[mi][ni][3]);
        size_t dst = (size_t)s * PER_S + ((size_t)(b * NH + h) * NSEQ + n) * DHEAD + d;
        *(uint2*)(qkv + dst) = o;
      }
    }
}

// ---------------- proj GEMM  C = A[8192,768] * B[768,768]^T + bias, 64x128 tiles
// BK=64 + T2 swizzle + XCD swizzle (768 = 8x96: A slice 1.6MB + B 1.2MB L2-fit).
__global__ __launch_bounds__(256)
void gemm_proj(const __hip_bfloat16* __restrict__ A, const __hip_bfloat16* __restrict__ Bw,
               float* __restrict__ Cf, const float* __restrict__ bias) {
  __shared__ __hip_bfloat16 As[64 * 64];    // row stride 128B, swizzled
  __shared__ __hip_bfloat16 Bs[128 * 64];
  const int t = threadIdx.x;
  const int lane = t & 63, w = t >> 6, g = lane >> 4, cg = lane & 15;
  // bijective XCD swizzle: 768 blocks = 8 XCDs x 96
  const int wgp = (blockIdx.x & 7) * 96 + (blockIdx.x >> 3);
  const int tm = wgp / 6, tn = wgp % 6;
  const char* Ab = (const char*)A + (size_t)tm * 64 * 768 * 2;
  const char* Bb = (const char*)Bw + (size_t)tn * 128 * 768 * 2;

  f32x4 z = {0.f, 0.f, 0.f, 0.f};
  f32x4 acc[4][2];
#pragma unroll
  for (int mi = 0; mi < 4; ++mi)
#pragma unroll
    for (int ni = 0; ni < 2; ++ni) acc[mi][ni] = z;

  const int rsw = (cg & 7);

  for (int k0 = 0; k0 < 768; k0 += 64) {
    __syncthreads();
#pragma unroll
    for (int i = 0; i < 2; ++i) {   // As: 8KB = 2 slots/thread
      int slot = t * 16 + i * 4096;
      int row = slot >> 7;
      int koff = (((slot & 127) >> 4) ^ (row & 7)) << 4;
      gload_lds16(Ab + (size_t)row * 1536 + k0 * 2 + koff, (char*)As + slot);
    }
#pragma unroll
    for (int i = 0; i < 4; ++i) {   // Bs: 16KB = 4 slots/thread
      int slot = t * 16 + i * 4096;
      int row = slot >> 7;
      int koff = (((slot & 127) >> 4) ^ (row & 7)) << 4;
      gload_lds16(Bb + (size_t)row * 1536 + k0 * 2 + koff, (char*)Bs + slot);
    }
    asm volatile("s_waitcnt vmcnt(0)" ::: "memory");
    __syncthreads();
#pragma unroll
    for (int h = 0; h < 2; ++h) {
      bf16x8 af[4], bf[2];
#pragma unroll
      for (int mi = 0; mi < 4; ++mi)
        af[mi] = *(const bf16x8*)((const char*)As + (mi * 16 + cg) * 128 +
                                  (((h * 4 + g) ^ rsw) << 4));
#pragma unroll
      for (int ni = 0; ni < 2; ++ni)
        bf[ni] = *(const bf16x8*)((const char*)Bs + (w * 32 + ni * 16 + cg) * 128 +
                                  (((h * 4 + g) ^ rsw) << 4));
#pragma unroll
      for (int mi = 0; mi < 4; ++mi)
#pragma unroll
        for (int ni = 0; ni < 2; ++ni)
          acc[mi][ni] = __builtin_amdgcn_mfma_f32_16x16x32_bf16(bf[ni], af[mi], acc[mi][ni], 0, 0, 0);
    }
  }

#pragma unroll
  for (int mi = 0; mi < 4; ++mi)
#pragma unroll
    for (int ni = 0; ni < 2; ++ni) {
      int grow = tm * 64 + mi * 16 + cg;
      int gcol = tn * 128 + w * 32 + ni * 16 + g * 4;
      float4 bv = *(const float4*)(bias + gcol);
      float4 ov;
      ov.x = acc[mi][ni][0] + bv.x;
      ov.y = acc[mi][ni][1] + bv.y;
      ov.z = acc[mi][ni][2] + bv.z;
      ov.w = acc[mi][ni][3] + bv.w;
      *(float4*)(Cf + (size_t)grow * CDIM + gcol) = ov;
    }
}

// ---------------- flash attention, swapped-operand 32x32x16, UNNORMALIZED exp2
// Round-8 proven structure (152.9 us): 2-buffer LDS K+V, __syncthreads pairs,
// vmcnt(0), setprio, hashed kv start, f32 tree-sum denominator.
struct QFrag { bf16x8 v[4]; };

static __device__ __forceinline__ void attn_tile(const char* __restrict__ Kb,
                                                 const char* __restrict__ Vb,
                                                 const QFrag& qf, int l31, int hi,
                                                 const f32x16& Z,
                                                 f32x16& o0, f32x16& o1, float& lsum) {
  const int swz = (l31 & 7) << 4;
  __builtin_amdgcn_s_setprio(1);
  bf16x8 ka = *(const bf16x8*)(Kb + l31 * 128 + ((hi * 16) ^ swz));
  bf16x8 kb = *(const bf16x8*)(Kb + (32 + l31) * 128 + ((hi * 16) ^ swz));
  f32x16 t0 = __builtin_amdgcn_mfma_f32_32x32x16_bf16(ka, qf.v[0], Z, 0, 0, 0);
  f32x16 t1 = __builtin_amdgcn_mfma_f32_32x32x16_bf16(kb, qf.v[0], Z, 0, 0, 0);
#pragma unroll
  for (int j = 1; j < 4; ++j) {
    bf16x8 kf0 = *(const bf16x8*)(Kb + l31 * 128 + ((j * 32 + hi * 16) ^ swz));
    bf16x8 kf1 = *(const bf16x8*)(Kb + (32 + l31) * 128 + ((j * 32 + hi * 16) ^ swz));
    t0 = __builtin_amdgcn_mfma_f32_32x32x16_bf16(kf0, qf.v[j], t0, 0, 0, 0);
    t1 = __builtin_amdgcn_mfma_f32_32x32x16_bf16(kf1, qf.v[j], t1, 0, 0, 0);
  }
  __builtin_amdgcn_s_setprio(0);

#pragma unroll
  for (int r = 0; r < 16; ++r) t0[r] = fexp2(t0[r]);
#pragma unroll
  for (int r = 0; r < 16; ++r) t1[r] = fexp2(t1[r]);

  // pairwise tree sum of own 32 kv (f32 P); cross-half combine deferred to epilogue
  float s0 = ((t0[0] + t0[1]) + (t0[2] + t0[3])) + ((t0[4] + t0[5]) + (t0[6] + t0[7]));
  float s1 = ((t0[8] + t0[9]) + (t0[10] + t0[11])) + ((t0[12] + t0[13]) + (t0[14] + t0[15]));
  float s2 = ((t1[0] + t1[1]) + (t1[2] + t1[3])) + ((t1[4] + t1[5]) + (t1[6] + t1[7]));
  float s3 = ((t1[8] + t1[9]) + (t1[10] + t1[11])) + ((t1[12] + t1[13]) + (t1[14] + t1[15]));
  lsum += (s0 + s1) + (s2 + s3);

  // P -> bf16 A-frags in-register (cvt_pk pairs, permlane32_swap halves)
  uint32_t w0[8], w1[8];
#pragma unroll
  for (int i = 0; i < 8; ++i) {
    w0[i] = pack2(t0[2 * i], t0[2 * i + 1]);
    w1[i] = pack2(t1[2 * i], t1[2 * i + 1]);
  }
  permswap(w0[0], w0[2]); permswap(w0[1], w0[3]);
  permswap(w0[4], w0[6]); permswap(w0[5], w0[7]);
  permswap(w1[0], w1[2]); permswap(w1[1], w1[3]);
  permswap(w1[4], w1[6]); permswap(w1[5], w1[7]);
  union { u32x4 u; bf16x8 b; } pa[4];
  pa[0].u = (u32x4){w0[0], w0[1], w0[2], w0[3]};
  pa[1].u = (u32x4){w0[4], w0[5], w0[6], w0[7]};
  pa[2].u = (u32x4){w1[0], w1[1], w1[2], w1[3]};
  pa[3].u = (u32x4){w1[4], w1[5], w1[6], w1[7]};

  // O += P V   (A = P-frag, B = V^T-frag from LDS)
  __builtin_amdgcn_s_setprio(1);
#pragma unroll
  for (int s = 0; s < 2; ++s)
#pragma unroll
    for (int j = 0; j < 2; ++j) {
      bf16x8 vf0 = *(const bf16x8*)(Vb + l31 * 128 + ((s * 64 + j * 32 + hi * 16) ^ swz));
      bf16x8 vf1 = *(const bf16x8*)(Vb + (32 + l31) * 128 + ((s * 64 + j * 32 + hi * 16) ^ swz));
      o0 = __builtin_amdgcn_mfma_f32_32x32x16_bf16(pa[s * 2 + j].b, vf0, o0, 0, 0, 0);
      o1 = __builtin_amdgcn_mfma_f32_32x32x16_bf16(pa[s * 2 + j].b, vf1, o1, 0, 0, 0);
    }
  __builtin_amdgcn_s_setprio(0);
}

__global__ __launch_bounds__(256)
void attn_kernel(const __hip_bfloat16* __restrict__ Qg,   // [bh][n][d]
                 const __hip_bfloat16* __restrict__ Kg,   // [bh][n][d]
                 const __hip_bfloat16* __restrict__ Vtg,  // [bh][d][n]
                 __hip_bfloat16* __restrict__ Og) {
  __shared__ char Ks[2][8192];
  __shared__ char Vs[2][8192];

  const int t = threadIdx.x;
  const int lane = t & 63, w = t >> 6;
  const int l31 = lane & 31, hi = lane >> 5;

  // bijective XCD swizzle: 768 blocks, 96/XCD -> each XCD owns 3 whole heads
  const int wg = (blockIdx.x & 7) * 96 + (blockIdx.x >> 3);
  const int bh = wg >> 5, qblk = wg & 31;
  // de-phase-lock co-resident blocks: hashed kv start tile (sum is order-invariant)
  const int start = (int)((wg * 2654435761u) >> 26) & 63;

  const char* Qb = (const char*)Qg + (size_t)bh * (NSEQ * DHEAD * 2);
  const char* Kb = (const char*)Kg + (size_t)bh * (NSEQ * DHEAD * 2);
  const char* Vb = (const char*)Vtg + (size_t)bh * (NSEQ * DHEAD * 2);

  // staging map: LDS slot p -> row=p>>7, col=(p&127); global src col pre-swizzled (m173)
  const int s0 = t * 16, s1 = t * 16 + 4096;
  const int r0 = s0 >> 7, c0 = (s0 & 127) ^ ((r0 & 7) << 4);
  const int r1 = s1 >> 7, c1 = (s1 & 127) ^ ((r1 & 7) << 4);
  const char* ks0 = Kb + r0 * 128 + c0;
  const char* ks1 = Kb + r1 * 128 + c1;
  const char* vs0 = Vb + (size_t)r0 * (NSEQ * 2) + c0;
  const char* vs1 = Vb + (size_t)r1 * (NSEQ * 2) + c1;

#define STAGE(buf, tile)                                            \
  do {                                                              \
    int kv0_ = (tile)*64;                                           \
    gload_lds16(ks0 + (size_t)kv0_ * 128, &Ks[buf][s0]);            \
    gload_lds16(ks1 + (size_t)kv0_ * 128, &Ks[buf][s1]);            \
    gload_lds16(vs0 + kv0_ * 2, &Vs[buf][s0]);                      \
    gload_lds16(vs1 + kv0_ * 2, &Vs[buf][s1]);                      \
  } while (0)

  // Q fragments (B-operand: n=q at lane&31, k=d slice at hi*16), 4 d-slices
  const int q0 = qblk * 128 + w * 32;
  QFrag qf;
#pragma unroll
  for (int j = 0; j < 4; ++j)
    qf.v[j] = *(const bf16x8*)(Qb + (size_t)(q0 + l31) * 128 + j * 32 + hi * 16);

  f32x16 o0, o1, Z;
#pragma unroll
  for (int r = 0; r < 16; ++r) { o0[r] = 0.f; o1[r] = 0.f; Z[r] = 0.f; }
  float lsum = 0.f;

  STAGE(0, start);
  asm volatile("s_waitcnt vmcnt(0)" ::: "memory");
  __syncthreads();

  for (int i = 0; i < 64; i += 2) {
    STAGE(1, (i + 1 + start) & 63);
    attn_tile(Ks[0], Vs[0], qf, l31, hi, Z, o0, o1, lsum);
    asm volatile("s_waitcnt vmcnt(0)" ::: "memory");
    __syncthreads();
    if (i + 2 < 64) STAGE(0, (i + 2 + start) & 63);
    attn_tile(Ks[1], Vs[1], qf, l31, hi, Z, o0, o1, lsum);
    asm volatile("s_waitcnt vmcnt(0)" ::: "memory");
    __syncthreads();
  }

  // epilogue: cross-half l combine (once per block), then divide + store
  {
    uint32_t c = __builtin_bit_cast(uint32_t, lsum), d = c;
    permswap(c, d);
    lsum = __builtin_bit_cast(float, c) + __builtin_bit_cast(float, d);
  }
  float linv = 1.0f / lsum;
  const int b = bh / NH, h = bh % NH;
#pragma unroll
  for (int r = 0; r < 16; ++r) {
    int ql = (r & 3) + 8 * (r >> 2) + 4 * hi;
    float lr = __shfl(linv, ql, 32);
    size_t base = (size_t)(b * NSEQ + q0 + ql) * CDIM + h * DHEAD;
    Og[base + l31] = __float2bfloat16(o0[r] * lr);
    Og[base + 32 + l31] = __float2bfloat16(o1[r] * lr);
  }
#undef STAGE
}

extern "C" void kernel_launch(void* const* d_in, const int* in_sizes, int n_in,
                              void* d_out, int out_size, void* d_ws, size_t ws_size,
                              hipStream_t stream) {
  const float* x = (const float*)d_in[0];
  const float* wqkv = (const float*)d_in[1];
  const float* wproj = (const float*)d_in[2];
  const float* bproj = (const float*)d_in[3];

  char* ws = (char*)d_ws;
  __hip_bfloat16* xb     = (__hip_bfloat16*)(ws);              // 12,582,912 B
  __hip_bfloat16* wqkvb  = (__hip_bfloat16*)(ws + 12582912);   //  3,538,944 B
  __hip_bfloat16* wprojb = (__hip_bfloat16*)(ws + 16121856);   //  1,179,648 B
  __hip_bfloat16* qkvws  = (__hip_bfloat16*)(ws + 17301504);   // 37,748,736 B
  __hip_bfloat16* attnws = (__hip_bfloat16*)(ws + 55050240);   // 12,582,912 B

  const float QSCALE = 0.125f * 1.44269504088896340736f;  // head_dim^-0.5 * log2(e)

  cvt_all<<<8448, 256, 0, stream>>>(x, wqkv, wproj, xb, QSCALE);

  gemm_qkv<<<64 * 18, 256, 0, stream>>>(xb, wqkvb, qkvws);

  attn_kernel<<<768, 256, 0, stream>>>(qkvws, qkvws + PER_S, qkvws + 2 * PER_S, attnws);

  gemm_proj<<<128 * 6, 256, 0, stream>>>(attnws, wprojb, (float*)d_out, bproj);
}

// Round 19
// 214.972 us; speedup vs baseline: 1.0939x; 1.0476x over previous
//
#include <hip/hip_runtime.h>
#include <hip/hip_bf16.h>
#include <stdint.h>

// Attention_9234179687676: x[2,4096,768] -> qkv -> 12-head attn (N=4096, D=64) -> proj+bias
// fp32 in/out, bf16 MFMA internally.

typedef short bf16x8 __attribute__((ext_vector_type(8)));
typedef float f32x4 __attribute__((ext_vector_type(4)));
typedef float f32x16 __attribute__((ext_vector_type(16)));
typedef uint32_t u32x4 __attribute__((ext_vector_type(4)));

#define B_SZ 2
#define NSEQ 4096
#define CDIM 768
#define NH 12
#define DHEAD 64
#define PER_S ((size_t)8192 * 768)

static __device__ __forceinline__ void gload_lds16(const void* g, void* l) {
  __builtin_amdgcn_global_load_lds(
      (const __attribute__((address_space(1))) uint32_t*)g,
      (__attribute__((address_space(3))) uint32_t*)l, 16, 0, 0);
}

// packed f32->bf16 (RNE): 1 instruction for 2 values
static __device__ __forceinline__ uint32_t pack2(float lo, float hi) {
  uint32_t r;
  asm("v_cvt_pk_bf16_f32 %0, %1, %2" : "=v"(r) : "v"(lo), "v"(hi));
  return r;
}

static __device__ __forceinline__ float fexp2(float x) {
#if __has_builtin(__builtin_amdgcn_exp2f)
  return __builtin_amdgcn_exp2f(x);   // raw v_exp_f32
#else
  return exp2f(x);
#endif
}

static __device__ __forceinline__ void permswap(uint32_t& a, uint32_t& b) {
#if __has_builtin(__builtin_amdgcn_permlane32_swap)
  auto r = __builtin_amdgcn_permlane32_swap((int)a, (int)b, false, false);
  a = (uint32_t)r[0];
  b = (uint32_t)r[1];
#else
  asm volatile("v_permlane32_swap_b32 %0, %1" : "+v"(a), "+v"(b));
#endif
}

// ---------------- single fused fp32 -> bf16 convert into contiguous ws region
// regions (float4 units): x [0,1572864) ; wqkv [1572864,2015232) with QSCALE on
// its first 147456 (= 768 Q rows x 768 / 4); wproj [2015232,2162688)
__global__ void cvt_all(const float* __restrict__ x, const float* __restrict__ wqkv,
                        const float* __restrict__ wproj, __hip_bfloat16* __restrict__ dst,
                        float qscale) {
  int i = blockIdx.x * 256 + threadIdx.x;
  if (i >= 2162688) return;
  const float* src;
  int off;
  float sc = 1.0f;
  if (i < 1572864) {
    src = x; off = 0;
  } else if (i < 2015232) {
    src = wqkv; off = 1572864;
    if (i < 1572864 + 147456) sc = qscale;
  } else {
    src = wproj; off = 2015232;
  }
  float4 v = ((const float4*)src)[i - off];
  uint2 o;
  o.x = pack2(v.x * sc, v.y * sc);
  o.y = pack2(v.z * sc, v.w * sc);
  ((uint2*)dst)[i] = o;
}

// ---------------- QKV GEMM  C = A[8192,768] * B[2304,768]^T, 64x128 tiles
// (retiled to the proven gemm_proj structure: ~805 TF vs 620 at 128x128).
// Grid 128x18 = 2304 blocks = exactly 9/CU (no co-residency imbalance).
// BK=64 + T2 XOR-swizzled LDS + XCD swizzle (8x288: A slice 1.6MB + B 3.5MB).
// MFMA operands swapped (mfma(bf,af)): reg-quad spans 4 consecutive gcols.
// Scatter: Q,K as [bh][n][d] (uint2); V as [bh][d][n] (4 scalar, transposed).
__global__ __launch_bounds__(256)
void gemm_qkv(const __hip_bfloat16* __restrict__ A, const __hip_bfloat16* __restrict__ Bw,
              __hip_bfloat16* __restrict__ qkv) {
  __shared__ __hip_bfloat16 As[64 * 64];    // row stride 128B, swizzled
  __shared__ __hip_bfloat16 Bs[128 * 64];
  const int t = threadIdx.x;
  const int lane = t & 63, w = t >> 6, g = lane >> 4, cg = lane & 15;
  // bijective XCD swizzle: 2304 blocks = 8 XCDs x 288
  const int wgq = ((int)blockIdx.x & 7) * 288 + ((int)blockIdx.x >> 3);
  const int tm = wgq / 18, tn = wgq % 18;
  const char* Ab = (const char*)A + (size_t)tm * 64 * 768 * 2;
  const char* Bb = (const char*)Bw + (size_t)tn * 128 * 768 * 2;

  f32x4 z = {0.f, 0.f, 0.f, 0.f};
  f32x4 acc[4][2];
#pragma unroll
  for (int mi = 0; mi < 4; ++mi)
#pragma unroll
    for (int ni = 0; ni < 2; ++ni) acc[mi][ni] = z;

  const int rsw = (cg & 7);

  for (int k0 = 0; k0 < 768; k0 += 64) {
    __syncthreads();
#pragma unroll
    for (int i = 0; i < 2; ++i) {   // As: 8KB = 2 slots/thread
      int slot = t * 16 + i * 4096;
      int row = slot >> 7;
      int koff = (((slot & 127) >> 4) ^ (row & 7)) << 4;
      gload_lds16(Ab + (size_t)row * 1536 + k0 * 2 + koff, (char*)As + slot);
    }
#pragma unroll
    for (int i = 0; i < 4; ++i) {   // Bs: 16KB = 4 slots/thread
      int slot = t * 16 + i * 4096;
      int row = slot >> 7;
      int koff = (((slot & 127) >> 4) ^ (row & 7)) << 4;
      gload_lds16(Bb + (size_t)row * 1536 + k0 * 2 + koff, (char*)Bs + slot);
    }
    asm volatile("s_waitcnt vmcnt(0)" ::: "memory");
    __syncthreads();
#pragma unroll
    for (int h = 0; h < 2; ++h) {
      bf16x8 af[4], bf[2];
#pragma unroll
      for (int mi = 0; mi < 4; ++mi)
        af[mi] = *(const bf16x8*)((const char*)As + (mi * 16 + cg) * 128 +
                                  (((h * 4 + g) ^ rsw) << 4));
#pragma unroll
      for (int ni = 0; ni < 2; ++ni)
        bf[ni] = *(const bf16x8*)((const char*)Bs + (w * 32 + ni * 16 + cg) * 128 +
                                  (((h * 4 + g) ^ rsw) << 4));
#pragma unroll
      for (int mi = 0; mi < 4; ++mi)
#pragma unroll
        for (int ni = 0; ni < 2; ++ni)
          acc[mi][ni] = __builtin_amdgcn_mfma_f32_16x16x32_bf16(bf[ni], af[mi], acc[mi][ni], 0, 0, 0);
    }
  }

  // scatter epilogue: 64 | 4096 so b,nb are uniform per block; quads (g*4) never
  // straddle head (64-aligned) or section (768-aligned) boundaries.
  const int b = (tm * 64) >> 12;
  const int nb = (tm * 64) & 4095;
#pragma unroll
  for (int mi = 0; mi < 4; ++mi)
#pragma unroll
    for (int ni = 0; ni < 2; ++ni) {
      int gcolb = tn * 128 + w * 32 + ni * 16 + g * 4;   // quad base (4 consecutive cols)
      int s = gcolb / CDIM, hd = gcolb % CDIM;
      int h = hd >> 6, d = hd & 63;
      int n = nb + mi * 16 + cg;
      if (s == 2) {
        // V^T [bh][d][n]: quad spans d -> 4 scalar stores at NSEQ stride
#pragma unroll
        for (int r = 0; r < 4; ++r) {
          size_t dst = 2 * PER_S + ((size_t)(b * NH + h) * DHEAD + d + r) * NSEQ + n;
          qkv[dst] = __float2bfloat16(acc[mi][ni][r]);
        }
      } else {
        // Q/K [bh][n][d]: quad spans d -> one uint2 store
        uint2 o;
        o.x = pack2(acc[mi][ni][0], acc[mi][ni][1]);
        o.y = pack2(acc[mi][ni][2], acc[mi][ni][3]);
        size_t dst = (size_t)s * PER_S + ((size_t)(b * NH + h) * NSEQ + n) * DHEAD + d;
        *(uint2*)(qkv + dst) = o;
      }
    }
}

// ---------------- proj GEMM  C = A[8192,768] * B[768,768]^T + bias, 64x128 tiles
// BK=64 + T2 swizzle + XCD swizzle (768 = 8x96: A slice 1.6MB + B 1.2MB L2-fit).
__global__ __launch_bounds__(256)
void gemm_proj(const __hip_bfloat16* __restrict__ A, const __hip_bfloat16* __restrict__ Bw,
               float* __restrict__ Cf, const float* __restrict__ bias) {
  __shared__ __hip_bfloat16 As[64 * 64];    // row stride 128B, swizzled
  __shared__ __hip_bfloat16 Bs[128 * 64];
  const int t = threadIdx.x;
  const int lane = t & 63, w = t >> 6, g = lane >> 4, cg = lane & 15;
  // bijective XCD swizzle: 768 blocks = 8 XCDs x 96
  const int wgp = ((int)blockIdx.x & 7) * 96 + ((int)blockIdx.x >> 3);
  const int tm = wgp / 6, tn = wgp % 6;
  const char* Ab = (const char*)A + (size_t)tm * 64 * 768 * 2;
  const char* Bb = (const char*)Bw + (size_t)tn * 128 * 768 * 2;

  f32x4 z = {0.f, 0.f, 0.f, 0.f};
  f32x4 acc[4][2];
#pragma unroll
  for (int mi = 0; mi < 4; ++mi)
#pragma unroll
    for (int ni = 0; ni < 2; ++ni) acc[mi][ni] = z;

  const int rsw = (cg & 7);

  for (int k0 = 0; k0 < 768; k0 += 64) {
    __syncthreads();
#pragma unroll
    for (int i = 0; i < 2; ++i) {   // As: 8KB = 2 slots/thread
      int slot = t * 16 + i * 4096;
      int row = slot >> 7;
      int koff = (((slot & 127) >> 4) ^ (row & 7)) << 4;
      gload_lds16(Ab + (size_t)row * 1536 + k0 * 2 + koff, (char*)As + slot);
    }
#pragma unroll
    for (int i = 0; i < 4; ++i) {   // Bs: 16KB = 4 slots/thread
      int slot = t * 16 + i * 4096;
      int row = slot >> 7;
      int koff = (((slot & 127) >> 4) ^ (row & 7)) << 4;
      gload_lds16(Bb + (size_t)row * 1536 + k0 * 2 + koff, (char*)Bs + slot);
    }
    asm volatile("s_waitcnt vmcnt(0)" ::: "memory");
    __syncthreads();
#pragma unroll
    for (int h = 0; h < 2; ++h) {
      bf16x8 af[4], bf[2];
#pragma unroll
      for (int mi = 0; mi < 4; ++mi)
        af[mi] = *(const bf16x8*)((const char*)As + (mi * 16 + cg) * 128 +
                                  (((h * 4 + g) ^ rsw) << 4));
#pragma unroll
      for (int ni = 0; ni < 2; ++ni)
        bf[ni] = *(const bf16x8*)((const char*)Bs + (w * 32 + ni * 16 + cg) * 128 +
                                  (((h * 4 + g) ^ rsw) << 4));
#pragma unroll
      for (int mi = 0; mi < 4; ++mi)
#pragma unroll
        for (int ni = 0; ni < 2; ++ni)
          acc[mi][ni] = __builtin_amdgcn_mfma_f32_16x16x32_bf16(bf[ni], af[mi], acc[mi][ni], 0, 0, 0);
    }
  }

#pragma unroll
  for (int mi = 0; mi < 4; ++mi)
#pragma unroll
    for (int ni = 0; ni < 2; ++ni) {
      int grow = tm * 64 + mi * 16 + cg;
      int gcol = tn * 128 + w * 32 + ni * 16 + g * 4;
      float4 bv = *(const float4*)(bias + gcol);
      float4 ov;
      ov.x = acc[mi][ni][0] + bv.x;
      ov.y = acc[mi][ni][1] + bv.y;
      ov.z = acc[mi][ni][2] + bv.z;
      ov.w = acc[mi][ni][3] + bv.w;
      *(float4*)(Cf + (size_t)grow * CDIM + gcol) = ov;
    }
}

// ---------------- flash attention, swapped-operand 32x32x16, UNNORMALIZED exp2
// Round-8 proven structure (152.9 us): 2-buffer LDS K+V, __syncthreads pairs,
// vmcnt(0), setprio, hashed kv start, f32 tree-sum denominator.
struct QFrag { bf16x8 v[4]; };

static __device__ __forceinline__ void attn_tile(const char* __restrict__ Kb,
                                                 const char* __restrict__ Vb,
                                                 const QFrag& qf, int l31, int hi,
                                                 const f32x16& Z,
                                                 f32x16& o0, f32x16& o1, float& lsum) {
  const int swz = (l31 & 7) << 4;
  __builtin_amdgcn_s_setprio(1);
  bf16x8 ka = *(const bf16x8*)(Kb + l31 * 128 + ((hi * 16) ^ swz));
  bf16x8 kb = *(const bf16x8*)(Kb + (32 + l31) * 128 + ((hi * 16) ^ swz));
  f32x16 t0 = __builtin_amdgcn_mfma_f32_32x32x16_bf16(ka, qf.v[0], Z, 0, 0, 0);
  f32x16 t1 = __builtin_amdgcn_mfma_f32_32x32x16_bf16(kb, qf.v[0], Z, 0, 0, 0);
#pragma unroll
  for (int j = 1; j < 4; ++j) {
    bf16x8 kf0 = *(const bf16x8*)(Kb + l31 * 128 + ((j * 32 + hi * 16) ^ swz));
    bf16x8 kf1 = *(const bf16x8*)(Kb + (32 + l31) * 128 + ((j * 32 + hi * 16) ^ swz));
    t0 = __builtin_amdgcn_mfma_f32_32x32x16_bf16(kf0, qf.v[j], t0, 0, 0, 0);
    t1 = __builtin_amdgcn_mfma_f32_32x32x16_bf16(kf1, qf.v[j], t1, 0, 0, 0);
  }
  __builtin_amdgcn_s_setprio(0);

#pragma unroll
  for (int r = 0; r < 16; ++r) t0[r] = fexp2(t0[r]);
#pragma unroll
  for (int r = 0; r < 16; ++r) t1[r] = fexp2(t1[r]);

  // pairwise tree sum of own 32 kv (f32 P); cross-half combine deferred to epilogue
  float s0 = ((t0[0] + t0[1]) + (t0[2] + t0[3])) + ((t0[4] + t0[5]) + (t0[6] + t0[7]));
  float s1 = ((t0[8] + t0[9]) + (t0[10] + t0[11])) + ((t0[12] + t0[13]) + (t0[14] + t0[15]));
  float s2 = ((t1[0] + t1[1]) + (t1[2] + t1[3])) + ((t1[4] + t1[5]) + (t1[6] + t1[7]));
  float s3 = ((t1[8] + t1[9]) + (t1[10] + t1[11])) + ((t1[12] + t1[13]) + (t1[14] + t1[15]));
  lsum += (s0 + s1) + (s2 + s3);

  // P -> bf16 A-frags in-register (cvt_pk pairs, permlane32_swap halves)
  uint32_t w0[8], w1[8];
#pragma unroll
  for (int i = 0; i < 8; ++i) {
    w0[i] = pack2(t0[2 * i], t0[2 * i + 1]);
    w1[i] = pack2(t1[2 * i], t1[2 * i + 1]);
  }
  permswap(w0[0], w0[2]); permswap(w0[1], w0[3]);
  permswap(w0[4], w0[6]); permswap(w0[5], w0[7]);
  permswap(w1[0], w1[2]); permswap(w1[1], w1[3]);
  permswap(w1[4], w1[6]); permswap(w1[5], w1[7]);
  union { u32x4 u; bf16x8 b; } pa[4];
  pa[0].u = (u32x4){w0[0], w0[1], w0[2], w0[3]};
  pa[1].u = (u32x4){w0[4], w0[5], w0[6], w0[7]};
  pa[2].u = (u32x4){w1[0], w1[1], w1[2], w1[3]};
  pa[3].u = (u32x4){w1[4], w1[5], w1[6], w1[7]};

  // O += P V   (A = P-frag, B = V^T-frag from LDS)
  __builtin_amdgcn_s_setprio(1);
#pragma unroll
  for (int s = 0; s < 2; ++s)
#pragma unroll
    for (int j = 0; j < 2; ++j) {
      bf16x8 vf0 = *(const bf16x8*)(Vb + l31 * 128 + ((s * 64 + j * 32 + hi * 16) ^ swz));
      bf16x8 vf1 = *(const bf16x8*)(Vb + (32 + l31) * 128 + ((s * 64 + j * 32 + hi * 16) ^ swz));
      o0 = __builtin_amdgcn_mfma_f32_32x32x16_bf16(pa[s * 2 + j].b, vf0, o0, 0, 0, 0);
      o1 = __builtin_amdgcn_mfma_f32_32x32x16_bf16(pa[s * 2 + j].b, vf1, o1, 0, 0, 0);
    }
  __builtin_amdgcn_s_setprio(0);
}

__global__ __launch_bounds__(256)
void attn_kernel(const __hip_bfloat16* __restrict__ Qg,   // [bh][n][d]
                 const __hip_bfloat16* __restrict__ Kg,   // [bh][n][d]
                 const __hip_bfloat16* __restrict__ Vtg,  // [bh][d][n]
                 __hip_bfloat16* __restrict__ Og) {
  __shared__ char Ks[2][8192];
  __shared__ char Vs[2][8192];

  const int t = threadIdx.x;
  const int lane = t & 63, w = t >> 6;
  const int l31 = lane & 31, hi = lane >> 5;

  // bijective XCD swizzle: 768 blocks, 96/XCD -> each XCD owns 3 whole heads
  const int wg = (blockIdx.x & 7) * 96 + (blockIdx.x >> 3);
  const int bh = wg >> 5, qblk = wg & 31;
  // de-phase-lock co-resident blocks: hashed kv start tile (sum is order-invariant)
  const int start = (int)((wg * 2654435761u) >> 26) & 63;

  const char* Qb = (const char*)Qg + (size_t)bh * (NSEQ * DHEAD * 2);
  const char* Kb = (const char*)Kg + (size_t)bh * (NSEQ * DHEAD * 2);
  const char* Vb = (const char*)Vtg + (size_t)bh * (NSEQ * DHEAD * 2);

  // staging map: LDS slot p -> row=p>>7, col=(p&127); global src col pre-swizzled (m173)
  const int s0 = t * 16, s1 = t * 16 + 4096;
  const int r0 = s0 >> 7, c0 = (s0 & 127) ^ ((r0 & 7) << 4);
  const int r1 = s1 >> 7, c1 = (s1 & 127) ^ ((r1 & 7) << 4);
  const char* ks0 = Kb + r0 * 128 + c0;
  const char* ks1 = Kb + r1 * 128 + c1;
  const char* vs0 = Vb + (size_t)r0 * (NSEQ * 2) + c0;
  const char* vs1 = Vb + (size_t)r1 * (NSEQ * 2) + c1;

#define STAGE(buf, tile)                                            \
  do {                                                              \
    int kv0_ = (tile)*64;                                           \
    gload_lds16(ks0 + (size_t)kv0_ * 128, &Ks[buf][s0]);            \
    gload_lds16(ks1 + (size_t)kv0_ * 128, &Ks[buf][s1]);            \
    gload_lds16(vs0 + kv0_ * 2, &Vs[buf][s0]);                      \
    gload_lds16(vs1 + kv0_ * 2, &Vs[buf][s1]);                      \
  } while (0)

  // Q fragments (B-operand: n=q at lane&31, k=d slice at hi*16), 4 d-slices
  const int q0 = qblk * 128 + w * 32;
  QFrag qf;
#pragma unroll
  for (int j = 0; j < 4; ++j)
    qf.v[j] = *(const bf16x8*)(Qb + (size_t)(q0 + l31) * 128 + j * 32 + hi * 16);

  f32x16 o0, o1, Z;
#pragma unroll
  for (int r = 0; r < 16; ++r) { o0[r] = 0.f; o1[r] = 0.f; Z[r] = 0.f; }
  float lsum = 0.f;

  STAGE(0, start);
  asm volatile("s_waitcnt vmcnt(0)" ::: "memory");
  __syncthreads();

  for (int i = 0; i < 64; i += 2) {
    STAGE(1, (i + 1 + start) & 63);
    attn_tile(Ks[0], Vs[0], qf, l31, hi, Z, o0, o1, lsum);
    asm volatile("s_waitcnt vmcnt(0)" ::: "memory");
    __syncthreads();
    if (i + 2 < 64) STAGE(0, (i + 2 + start) & 63);
    attn_tile(Ks[1], Vs[1], qf, l31, hi, Z, o0, o1, lsum);
    asm volatile("s_waitcnt vmcnt(0)" ::: "memory");
    __syncthreads();
  }

  // epilogue: cross-half l combine (once per block), then divide + store
  {
    uint32_t c = __builtin_bit_cast(uint32_t, lsum), d = c;
    permswap(c, d);
    lsum = __builtin_bit_cast(float, c) + __builtin_bit_cast(float, d);
  }
  float linv = 1.0f / lsum;
  const int b = bh / NH, h = bh % NH;
#pragma unroll
  for (int r = 0; r < 16; ++r) {
    int ql = (r & 3) + 8 * (r >> 2) + 4 * hi;
    float lr = __shfl(linv, ql, 32);
    size_t base = (size_t)(b * NSEQ + q0 + ql) * CDIM + h * DHEAD;
    Og[base + l31] = __float2bfloat16(o0[r] * lr);
    Og[base + 32 + l31] = __float2bfloat16(o1[r] * lr);
  }
#undef STAGE
}

extern "C" void kernel_launch(void* const* d_in, const int* in_sizes, int n_in,
                              void* d_out, int out_size, void* d_ws, size_t ws_size,
                              hipStream_t stream) {
  const float* x = (const float*)d_in[0];
  const float* wqkv = (const float*)d_in[1];
  const float* wproj = (const float*)d_in[2];
  const float* bproj = (const float*)d_in[3];

  char* ws = (char*)d_ws;
  __hip_bfloat16* xb     = (__hip_bfloat16*)(ws);              // 12,582,912 B
  __hip_bfloat16* wqkvb  = (__hip_bfloat16*)(ws + 12582912);   //  3,538,944 B
  __hip_bfloat16* wprojb = (__hip_bfloat16*)(ws + 16121856);   //  1,179,648 B
  __hip_bfloat16* qkvws  = (__hip_bfloat16*)(ws + 17301504);   // 37,748,736 B
  __hip_bfloat16* attnws = (__hip_bfloat16*)(ws + 55050240);   // 12,582,912 B

  const float QSCALE = 0.125f * 1.44269504088896340736f;  // head_dim^-0.5 * log2(e)

  cvt_all<<<8448, 256, 0, stream>>>(x, wqkv, wproj, xb, QSCALE);

  gemm_qkv<<<2304, 256, 0, stream>>>(xb, wqkvb, qkvws);

  attn_kernel<<<768, 256, 0, stream>>>(qkvws, qkvws + PER_S, qkvws + 2 * PER_S, attnws);

  gemm_proj<<<128 * 6, 256, 0, stream>>>(attnws, wprojb, (float*)d_out, bproj);
}